// Round 10
// baseline (235.653 us; speedup 1.0000x reference)
//
#include <hip/hip_runtime.h>

// ---------------------------------------------------------------------------
// Res_up block, round 10: round 9 + agg restructured block-per-node (4 waves
// split the edge bucket, LDS reduce) with software-pipelined prefetch and
// interleaved knn meta. Everything else unchanged.
// 10 dispatches.
// Sizes fixed: Nc=4096, Nf=16384, Ec=65536, Ef=262144, Cin=128, Ch=64, Co=128.
// ---------------------------------------------------------------------------

#define SELU_SCALE 1.0507009873554805f
#define SELU_ALPHA 1.6732632423543772f

static constexpr int NC = 4096, NF = 16384, EC = 65536, EF = 262144;
static constexpr int G = 32, NCELL = G * G;

typedef __attribute__((ext_vector_type(8))) short short8v;
typedef __attribute__((ext_vector_type(4))) float f32x4;
typedef unsigned short ushort_t;
typedef unsigned long long u64;

__device__ __forceinline__ float selu_f(float x) {
    return x > 0.0f ? SELU_SCALE * x
                    : SELU_SCALE * SELU_ALPHA * (__expf(x) - 1.0f);
}
__device__ __forceinline__ ushort_t f2bf(float f) {
    unsigned u = __float_as_uint(f);
    u += 0x7FFFu + ((u >> 16) & 1u);
    return (ushort_t)(u >> 16);
}
__device__ __forceinline__ float bf2f(ushort_t u) {
    return __uint_as_float(((unsigned)u) << 16);
}
__device__ __forceinline__ int cell_of(float2 p) {
    int cx = (int)(p.x * (float)G); cx = cx > G - 1 ? G - 1 : cx;
    int cy = (int)(p.y * (float)G); cy = cy > G - 1 ? G - 1 : cy;
    return cy * G + cx;
}
__device__ __forceinline__ void ins3(u64& a0, u64& a1, u64& a2, u64 v) {
    if (v < a2) {
        if (v < a1) {
            a2 = a1;
            if (v < a0) { a1 = a0; a0 = v; } else a1 = v;
        } else a2 = v;
    }
}

// ---------------------------------------------------------------------------
// Fragment-major weight writer: Wf[(ntile*KC+kc)*512 + lane*8 + e] = W[k][col]
// ---------------------------------------------------------------------------
template <int K, typename F>
__device__ __forceinline__ void wfrag(F getw, ushort_t* __restrict__ dst, int idx) {
    constexpr int KC = K / 32;
    const int f = idx >> 9;
    const int r = idx & 511;
    const int lane = r >> 3;
    const int e = r & 7;
    const int ntile = f / KC;
    const int kc = f - ntile * KC;
    const int k = kc * 32 + ((lane >> 4) << 3) + e;
    const int col = ntile * 16 + (lane & 15);
    dst[idx] = f2bf(getw(k, col));
}

// ---------------------------------------------------------------------------
// prep: x->bf16, 5 weight-frag buffers, zero cnt/stats.
// ---------------------------------------------------------------------------
__global__ __launch_bounds__(256) void prep_kernel(
    const float* __restrict__ x, ushort_t* __restrict__ xb,
    const float* __restrict__ WeS, const float* __restrict__ WnS,
    const float* __restrict__ We1, const float* __restrict__ We2,
    const float* __restrict__ Wn2, const float* __restrict__ Wn1,
    ushort_t* __restrict__ WfA, ushort_t* __restrict__ WfE,
    ushort_t* __restrict__ WfSn, ushort_t* __restrict__ Wf1n,
    ushort_t* __restrict__ Wf2n,
    int* __restrict__ cntF, int* __restrict__ cntC, int* __restrict__ cntG,
    float* __restrict__ stats) {
    int i = blockIdx.x * 256 + threadIdx.x;
    if (i < NC * 128) { xb[i] = f2bf(x[i]); return; }
    i -= NC * 128;
    if (i < 65536) {   // RA weights: K=128, N=512
        wfrag<128>([&](int k, int j) {
            return j < 128 ? WeS[k * 128 + j]
                 : j < 256 ? WeS[(128 + k) * 128 + (j - 128)]
                 : j < 384 ? WnS[k * 128 + (j - 256)]
                 : j < 448 ? We1[k * 64 + (j - 384)]
                           : We1[(128 + k) * 64 + (j - 448)];
        }, WfA, i);
        return;
    }
    i -= 65536;
    if (i < 24576) {   // RE weights: K=64, N=384
        wfrag<64>([&](int k, int j) {
            return j < 128 ? We2[k * 128 + j]
                 : j < 256 ? We2[(64 + k) * 128 + (j - 128)]
                           : Wn2[k * 128 + (j - 256)];
        }, WfE, i);
        return;
    }
    i -= 24576;
    if (i < 16384) {   // nodeS: WnS bottom half, K=128, N=128
        wfrag<128>([&](int k, int j) { return WnS[(128 + k) * 128 + j]; }, WfSn, i);
        return;
    }
    i -= 16384;
    if (i < 12288) {   // node1: full Wn1, K=192, N=64
        wfrag<192>([&](int k, int j) { return Wn1[k * 64 + j]; }, Wf1n, i);
        return;
    }
    i -= 12288;
    if (i < 16384) {   // nodeH: Wn2 bottom, K=128, N=128
        wfrag<128>([&](int k, int j) { return Wn2[(64 + k) * 128 + j]; }, Wf2n, i);
        return;
    }
    i -= 16384;
    if (i < NF) { cntF[i] = 0; return; }
    i -= NF;
    if (i < NC) { cntC[i] = 0; return; }
    i -= NC;
    if (i < NCELL) { cntG[i] = 0; return; }
    i -= NCELL;
    if (i < 256) { stats[i] = 0.0f; return; }
}

// ---------------------------------------------------------------------------
// merged histogram / scan / scatter for {fine edges, coarse edges, grid cells}
// ---------------------------------------------------------------------------
__global__ __launch_bounds__(256) void hist3_kernel(
    const int* __restrict__ ei_f, const int* __restrict__ ei_c,
    const float* __restrict__ pos_c,
    int* __restrict__ cntF, int* __restrict__ cntC, int* __restrict__ cntG) {
    int i = blockIdx.x * 256 + threadIdx.x;
    if (i < EF) { atomicAdd(&cntF[ei_f[EF + i]], 1); return; }
    i -= EF;
    if (i < EC) { atomicAdd(&cntC[ei_c[EC + i]], 1); return; }
    i -= EC;
    if (i < NC) {
        float2 p = ((const float2*)pos_c)[i];
        atomicAdd(&cntG[cell_of(p)], 1);
    }
}

__global__ __launch_bounds__(1024) void scan3_kernel(
    int* __restrict__ cntF, int* __restrict__ baseF, int* __restrict__ cursF,
    int* __restrict__ cntC, int* __restrict__ baseC, int* __restrict__ cursC,
    int* __restrict__ cntG, int* __restrict__ baseG, int* __restrict__ cursG) {
    const int* cnt; int* base; int* curs; int n;
    if (blockIdx.x == 0)      { cnt = cntF; base = baseF; curs = cursF; n = NF; }
    else if (blockIdx.x == 1) { cnt = cntC; base = baseC; curs = cursC; n = NC; }
    else                      { cnt = cntG; base = baseG; curs = cursG; n = NCELL; }
    const int IT = n >> 10;
    __shared__ int part[1024];
    const int t = threadIdx.x;
    int loc[16];
    int s = 0;
#pragma unroll
    for (int i = 0; i < 16; ++i) {
        int v = (i < IT) ? cnt[t * IT + i] : 0;
        loc[i] = v; s += v;
    }
    part[t] = s;
    __syncthreads();
    for (int off = 1; off < 1024; off <<= 1) {
        int v = part[t];
        int u = (t >= off) ? part[t - off] : 0;
        __syncthreads();
        part[t] = v + u;
        __syncthreads();
    }
    int ex = (t == 0) ? 0 : part[t - 1];
#pragma unroll
    for (int i = 0; i < 16; ++i) {
        if (i < IT) {
            base[t * IT + i] = ex;
            curs[t * IT + i] = ex;
            ex += loc[i];
        }
    }
    if (t == 1023) base[n] = ex;
}

__global__ __launch_bounds__(256) void scatter3_kernel(
    const int* __restrict__ ei_f, const int* __restrict__ ei_c,
    const float* __restrict__ pos_c,
    int* __restrict__ cursF, int* __restrict__ srtF,
    int* __restrict__ cursC, int* __restrict__ srtC,
    int* __restrict__ cursG, float4* __restrict__ grecs) {
    int i = blockIdx.x * 256 + threadIdx.x;
    if (i < EF) {
        int pos = atomicAdd(&cursF[ei_f[EF + i]], 1);
        srtF[pos] = ei_f[i];
        return;
    }
    i -= EF;
    if (i < EC) {
        int pos = atomicAdd(&cursC[ei_c[EC + i]], 1);
        srtC[pos] = ei_c[i];
        return;
    }
    i -= EC;
    if (i < NC) {
        float2 p = ((const float2*)pos_c)[i];
        int pos = atomicAdd(&cursG[cell_of(p)], 1);
        float4 rec;
        rec.x = p.x; rec.y = p.y; rec.z = __int_as_float(i); rec.w = 0.0f;
        grecs[pos] = rec;
    }
}

// ---------------------------------------------------------------------------
// Fused: blocks 0..255 = RA GEMM (4096x512x128, bf16 out);
// blocks 256..767 = grid-kNN, 8 lanes per fine point.
// meta[2t] = idx bits (as float), meta[2t+1] = weights.
// ---------------------------------------------------------------------------
__global__ __launch_bounds__(256) void gemmA_knn_kernel(
    const ushort_t* __restrict__ xb, const ushort_t* __restrict__ WfA,
    ushort_t* __restrict__ RA,
    const float* __restrict__ pos_f, const float4* __restrict__ grecs,
    const int* __restrict__ baseG, float4* __restrict__ meta) {
    const int bid = blockIdx.x;
    const int tid = threadIdx.x;
    if (bid < 256) {
        const int wid = tid >> 6, lane = tid & 63;
        const int bx = bid >> 2, by = bid & 3;
        const int row_base = bx * 64 + wid * 16;
        const int row_a = row_base + (lane & 15);
        const int klane = (lane >> 4) << 3;
        short8v a[4];
#pragma unroll
        for (int f = 0; f < 4; ++f)
            a[f] = *(const short8v*)(xb + (size_t)row_a * 128 + f * 32 + klane);
#pragma unroll
        for (int nt = 0; nt < 8; ++nt) {
            const int ntg = by * 8 + nt;
            f32x4 acc = {0.0f, 0.0f, 0.0f, 0.0f};
#pragma unroll
            for (int f = 0; f < 4; ++f) {
                const short8v b =
                    *(const short8v*)(WfA + (size_t)(ntg * 4 + f) * 512 + lane * 8);
                acc = __builtin_amdgcn_mfma_f32_16x16x32_bf16(a[f], b, acc, 0, 0, 0);
            }
            const int col = ntg * 16 + (lane & 15);
            const int r0 = row_base + ((lane >> 4) << 2);
#pragma unroll
            for (int r = 0; r < 4; ++r)
                RA[(size_t)(r0 + r) * 512 + col] = f2bf(acc[r]);
        }
    } else {
        const int g8 = (bid - 256) * 256 + tid;    // 131072 = 8 * NF
        const int t = g8 >> 3;
        const int sub = g8 & 7;
        const float2 p = ((const float2*)pos_f)[t];
        int cx = (int)(p.x * (float)G); cx = cx > G - 1 ? G - 1 : cx;
        int cy = (int)(p.y * (float)G); cy = cy > G - 1 ? G - 1 : cy;
        const float h = 1.0f / (float)G;

        u64 b0 = ~0ull, b1 = ~0ull, b2 = ~0ull;

        {
            const int xx0 = cx - 1 < 0 ? 0 : cx - 1;
            const int xx1 = cx + 1 > G - 1 ? G - 1 : cx + 1;
            const int yy0 = cy - 1 < 0 ? 0 : cy - 1;
            const int yy1 = cy + 1 > G - 1 ? G - 1 : cy + 1;
            int rs[3], rl[3];
            int nr = 0;
            for (int yy = yy0; yy <= yy1; ++yy) {
                const int s = baseG[yy * G + xx0];
                const int e = baseG[yy * G + xx1 + 1];
                rs[nr] = s; rl[nr] = e - s; ++nr;
            }
            const int l0 = rl[0];
            const int l01 = l0 + (nr > 1 ? rl[1] : 0);
            const int m = l01 + (nr > 2 ? rl[2] : 0);
            for (int j = sub; j < m; j += 8) {
                int i;
                if (j < l0) i = rs[0] + j;
                else if (j < l01) i = rs[1] + (j - l0);
                else i = rs[2] + (j - l01);
                const float4 q = grecs[i];
                const float dx = p.x - q.x;
                const float dy = p.y - q.y;
                const float d = dx * dx + dy * dy;
                ins3(b0, b1, b2, ((u64)__float_as_uint(d) << 32) |
                                 (u64)__float_as_uint(q.z));
            }
#pragma unroll
            for (int mk = 1; mk <= 4; mk <<= 1) {
                const u64 e0 = __shfl_xor(b0, mk);
                const u64 e1 = __shfl_xor(b1, mk);
                const u64 e2 = __shfl_xor(b2, mk);
                ins3(b0, b1, b2, e0);
                ins3(b0, b1, b2, e1);
                ins3(b0, b1, b2, e2);
            }
        }

        for (int r = 2; r < G; ++r) {
            const float bd = __uint_as_float((unsigned)(b2 >> 32));
            const float lim = (float)(r - 1) * h;
            if (bd < lim * lim) break;
            u64 c0 = ~0ull, c1 = ~0ull, c2 = ~0ull;
            auto scan_cells = [&](int cell0, int cell1, int step) {
                for (int c = cell0; c <= cell1; c += step) {
                    const int s0 = baseG[c], s1 = baseG[c + 1];
                    for (int i = s0; i < s1; ++i) {
                        const float4 q = grecs[i];
                        const float dx = p.x - q.x;
                        const float dy = p.y - q.y;
                        const float d = dx * dx + dy * dy;
                        ins3(c0, c1, c2, ((u64)__float_as_uint(d) << 32) |
                                         (u64)__float_as_uint(q.z));
                    }
                }
            };
            const int side = sub & 3, phase = sub >> 2;
            const int x0 = cx - r < 0 ? 0 : cx - r;
            const int x1 = cx + r > G - 1 ? G - 1 : cx + r;
            const int yi0 = cy - r + 1 < 0 ? 0 : cy - r + 1;
            const int yi1 = cy + r - 1 > G - 1 ? G - 1 : cy + r - 1;
            if (side == 0) {
                if (cy - r >= 0) scan_cells((cy - r) * G + x0 + phase, (cy - r) * G + x1, 2);
            } else if (side == 1) {
                if (cy + r <= G - 1) scan_cells((cy + r) * G + x0 + phase, (cy + r) * G + x1, 2);
            } else if (side == 2) {
                if (cx - r >= 0 && yi0 + phase <= yi1)
                    scan_cells((yi0 + phase) * G + cx - r, yi1 * G + cx - r, 2 * G);
            } else {
                if (cx + r <= G - 1 && yi0 + phase <= yi1)
                    scan_cells((yi0 + phase) * G + cx + r, yi1 * G + cx + r, 2 * G);
            }
#pragma unroll
            for (int mk = 1; mk <= 4; mk <<= 1) {
                const u64 e0 = __shfl_xor(c0, mk);
                const u64 e1 = __shfl_xor(c1, mk);
                const u64 e2 = __shfl_xor(c2, mk);
                ins3(c0, c1, c2, e0);
                ins3(c0, c1, c2, e1);
                ins3(c0, c1, c2, e2);
            }
            ins3(b0, b1, b2, c0);
            ins3(b0, b1, b2, c1);
            ins3(b0, b1, b2, c2);
        }

        if (sub == 0) {
            const float d0 = __uint_as_float((unsigned)(b0 >> 32));
            const float d1 = __uint_as_float((unsigned)(b1 >> 32));
            const float d2 = __uint_as_float((unsigned)(b2 >> 32));
            const float w0 = 1.0f / fmaxf(d0, 1e-16f);
            const float w1 = 1.0f / fmaxf(d1, 1e-16f);
            const float w2 = 1.0f / fmaxf(d2, 1e-16f);
            const float s = 1.0f / (w0 + w1 + w2);
            float4 mi;
            mi.x = __uint_as_float((unsigned)(b0 & 0xffffffffu));
            mi.y = __uint_as_float((unsigned)(b1 & 0xffffffffu));
            mi.z = __uint_as_float((unsigned)(b2 & 0xffffffffu));
            mi.w = 0.0f;
            float4 mw;
            mw.x = w0 * s; mw.y = w1 * s; mw.z = w2 * s; mw.w = 0.0f;
            meta[2 * t] = mi;
            meta[2 * t + 1] = mw;
        }
    }
}

// ---------------------------------------------------------------------------
// agg, block-per-node: 4 waves split the edge bucket (stride 4), LDS reduce.
// Per node: Qf = interp(Q cols)+be (all waves), Uf = interp(U cols) (wave 0),
// agg = sum_e selu(interp_e(P cols) + Qf). Edge loop software-pipelined.
// DUAL: blocks NF.. handle coarse agg1 (RA cols 384..511, no interp).
// ---------------------------------------------------------------------------
template <int STRIDE, bool DUAL>
__global__ __launch_bounds__(256) void agg_kernel(
    const ushort_t* __restrict__ R, const float4* __restrict__ meta,
    const int* __restrict__ baseF, const int* __restrict__ srtF,
    const float* __restrict__ beF, ushort_t* __restrict__ aggF,
    ushort_t* __restrict__ Uf,
    const int* __restrict__ baseC, const int* __restrict__ srtC,
    const float* __restrict__ beC, ushort_t* __restrict__ aggC) {
    __shared__ float redx[4][64], redy[4][64];
    const int bid = blockIdx.x;
    const int wid = threadIdx.x >> 6, lane = threadIdx.x & 63;
    if (!DUAL || bid < NF) {
        const int n = bid;
        const float4 mi = meta[2 * n];
        const float4 mw = meta[2 * n + 1];
        const int i0 = (int)__float_as_uint(mi.x);
        const int i1 = (int)__float_as_uint(mi.y);
        const int i2 = (int)__float_as_uint(mi.z);
        const ushort_t* r0 = R + (size_t)i0 * STRIDE + lane * 2;
        const ushort_t* r1 = R + (size_t)i1 * STRIDE + lane * 2;
        const ushort_t* r2 = R + (size_t)i2 * STRIDE + lane * 2;
        // Q interp + bias (all waves need it)
        const float2 bv = *(const float2*)(beF + lane * 2);
        ushort2 a0 = *(const ushort2*)(r0 + 128);
        ushort2 a1 = *(const ushort2*)(r1 + 128);
        ushort2 a2 = *(const ushort2*)(r2 + 128);
        const float qx = mw.x * bf2f(a0.x) + mw.y * bf2f(a1.x) + mw.z * bf2f(a2.x) + bv.x;
        const float qy = mw.x * bf2f(a0.y) + mw.y * bf2f(a1.y) + mw.z * bf2f(a2.y) + bv.y;
        // U interp -> Uf (wave 0 only)
        if (wid == 0) {
            a0 = *(const ushort2*)(r0 + 256);
            a1 = *(const ushort2*)(r1 + 256);
            a2 = *(const ushort2*)(r2 + 256);
            ushort2 uo;
            uo.x = f2bf(mw.x * bf2f(a0.x) + mw.y * bf2f(a1.x) + mw.z * bf2f(a2.x));
            uo.y = f2bf(mw.x * bf2f(a0.y) + mw.y * bf2f(a1.y) + mw.z * bf2f(a2.y));
            *(ushort2*)(Uf + (size_t)n * 128 + lane * 2) = uo;
        }
        // edge loop, stride 4 across waves, pipelined 1 deep
        const int b0 = baseF[n], b1 = baseF[n + 1];
        float ax = 0.0f, ay = 0.0f;
        int e = b0 + wid;
        if (e < b1) {
            int src = srtF[e];
            float4 smi = meta[2 * src];
            float4 smw = meta[2 * src + 1];
            while (true) {
                const int en = e + 4;
                int srcn = 0;
                float4 nmi, nmw;
                const bool more = en < b1;
                if (more) {
                    srcn = srtF[en];
                    nmi = meta[2 * srcn];
                    nmw = meta[2 * srcn + 1];
                }
                const int s0 = (int)__float_as_uint(smi.x);
                const int s1 = (int)__float_as_uint(smi.y);
                const int s2 = (int)__float_as_uint(smi.z);
                const ushort2 p0 = *(const ushort2*)(R + (size_t)s0 * STRIDE + lane * 2);
                const ushort2 p1 = *(const ushort2*)(R + (size_t)s1 * STRIDE + lane * 2);
                const ushort2 p2 = *(const ushort2*)(R + (size_t)s2 * STRIDE + lane * 2);
                const float px = smw.x * bf2f(p0.x) + smw.y * bf2f(p1.x) + smw.z * bf2f(p2.x);
                const float py = smw.x * bf2f(p0.y) + smw.y * bf2f(p1.y) + smw.z * bf2f(p2.y);
                ax += selu_f(px + qx);
                ay += selu_f(py + qy);
                if (!more) break;
                e = en; smi = nmi; smw = nmw;
            }
        }
        redx[wid][lane] = ax;
        redy[wid][lane] = ay;
        __syncthreads();
        if (wid == 0) {
            const float sx = redx[0][lane] + redx[1][lane] + redx[2][lane] + redx[3][lane];
            const float sy = redy[0][lane] + redy[1][lane] + redy[2][lane] + redy[3][lane];
            ushort2 r; r.x = f2bf(sx); r.y = f2bf(sy);
            *(ushort2*)(aggF + (size_t)n * 128 + lane * 2) = r;
        }
    } else {
        const int n = bid - NF;
        const int b0 = baseC[n], b1 = baseC[n + 1];
        const float q = bf2f(R[(size_t)n * 512 + 448 + lane]) + beC[lane];
        float s = 0.0f;
        for (int e = b0 + wid; e < b1; e += 4)
            s += selu_f(bf2f(R[(size_t)srtC[e] * 512 + 384 + lane]) + q);
        redx[wid][lane] = s;
        __syncthreads();
        if (wid == 0) {
            const float t = redx[0][lane] + redx[1][lane] + redx[2][lane] + redx[3][lane];
            aggC[(size_t)n * 64 + lane] = f2bf(t);
        }
    }
}

// ---------------------------------------------------------------------------
// nodeSD: blocks 0..255: x_skip = selu(aggF@WnS_bot + UfS + bnS) -> outp f32
//         blocks 256..319: h1 = selu(concat(xb,agg1b)@Wn1 + bn1) in LDS,
//                          then RE = h1 @ WfE (fused gemmE) -> RE bf16
// ---------------------------------------------------------------------------
__global__ __launch_bounds__(256) void nodeSD_kernel(
    const ushort_t* __restrict__ aggF, const ushort_t* __restrict__ WfSn,
    const float* __restrict__ bnS, const ushort_t* __restrict__ UfS,
    float* __restrict__ outp,
    const ushort_t* __restrict__ xb, const ushort_t* __restrict__ agg1b,
    const ushort_t* __restrict__ Wf1n, const float* __restrict__ bn1,
    const ushort_t* __restrict__ WfE, ushort_t* __restrict__ RE) {
    __shared__ ushort_t h1s[64][72];
    const int tid = threadIdx.x;
    const int wid = tid >> 6, lane = tid & 63;
    const int klane = (lane >> 4) << 3;
    if (blockIdx.x < 256) {
        const int row_base = blockIdx.x * 64 + wid * 16;
        const int row_a = row_base + (lane & 15);
        short8v a[4];
#pragma unroll
        for (int f = 0; f < 4; ++f)
            a[f] = *(const short8v*)(aggF + (size_t)row_a * 128 + f * 32 + klane);
#pragma unroll
        for (int nt = 0; nt < 8; ++nt) {
            f32x4 acc = {0.0f, 0.0f, 0.0f, 0.0f};
#pragma unroll
            for (int f = 0; f < 4; ++f) {
                const short8v b =
                    *(const short8v*)(WfSn + (size_t)(nt * 4 + f) * 512 + lane * 8);
                acc = __builtin_amdgcn_mfma_f32_16x16x32_bf16(a[f], b, acc, 0, 0, 0);
            }
            const int col = nt * 16 + (lane & 15);
            const int r0 = row_base + ((lane >> 4) << 2);
#pragma unroll
            for (int r = 0; r < 4; ++r) {
                const size_t o = (size_t)(r0 + r) * 128 + col;
                outp[o] = selu_f(acc[r] + bnS[col] + bf2f(UfS[o]));
            }
        }
    } else {
        const int row_base = (blockIdx.x - 256) * 64 + wid * 16;
        const int row_a = row_base + (lane & 15);
        short8v a[6];
#pragma unroll
        for (int f = 0; f < 4; ++f)
            a[f] = *(const short8v*)(xb + (size_t)row_a * 128 + f * 32 + klane);
#pragma unroll
        for (int f = 0; f < 2; ++f)
            a[4 + f] = *(const short8v*)(agg1b + (size_t)row_a * 64 + f * 32 + klane);
#pragma unroll
        for (int nt = 0; nt < 4; ++nt) {
            f32x4 acc = {0.0f, 0.0f, 0.0f, 0.0f};
#pragma unroll
            for (int f = 0; f < 6; ++f) {
                const short8v b =
                    *(const short8v*)(Wf1n + (size_t)(nt * 6 + f) * 512 + lane * 8);
                acc = __builtin_amdgcn_mfma_f32_16x16x32_bf16(a[f], b, acc, 0, 0, 0);
            }
            const int col = nt * 16 + (lane & 15);
            const int lr0 = wid * 16 + ((lane >> 4) << 2);
#pragma unroll
            for (int r = 0; r < 4; ++r)
                h1s[lr0 + r][col] = f2bf(selu_f(acc[r] + bn1[col]));
        }
        __syncthreads();
        short8v ha[2];
#pragma unroll
        for (int f = 0; f < 2; ++f)
            ha[f] = *(const short8v*)&h1s[wid * 16 + (lane & 15)][f * 32 + klane];
#pragma unroll
        for (int nt = 0; nt < 24; ++nt) {
            f32x4 acc = {0.0f, 0.0f, 0.0f, 0.0f};
#pragma unroll
            for (int f = 0; f < 2; ++f) {
                const short8v b =
                    *(const short8v*)(WfE + (size_t)(nt * 2 + f) * 512 + lane * 8);
                acc = __builtin_amdgcn_mfma_f32_16x16x32_bf16(ha[f], b, acc, 0, 0, 0);
            }
            const int col = nt * 16 + (lane & 15);
            const int r0 = row_base + ((lane >> 4) << 2);
#pragma unroll
            for (int r = 0; r < 4; ++r)
                RE[(size_t)(r0 + r) * 384 + col] = f2bf(acc[r]);
        }
    }
}

// ---------------------------------------------------------------------------
// nodeH: v = selu(aggF@Wn2_bot + Uf2 + bn2) + x_skip; write outp; BN stats.
// ---------------------------------------------------------------------------
__global__ __launch_bounds__(256) void nodeH_kernel(
    const ushort_t* __restrict__ aggF, const ushort_t* __restrict__ Wf2n,
    const float* __restrict__ bn2, const ushort_t* __restrict__ Uf2,
    float* __restrict__ outp, float* __restrict__ stats) {
    __shared__ float s_sum[128], s_sq[128];
    const int tid = threadIdx.x;
    const int wid = tid >> 6, lane = tid & 63;
    const int klane = (lane >> 4) << 3;
    if (tid < 128) { s_sum[tid] = 0.0f; s_sq[tid] = 0.0f; }
    __syncthreads();
    const int row_base = blockIdx.x * 64 + wid * 16;
    const int row_a = row_base + (lane & 15);
    short8v a[4];
#pragma unroll
    for (int f = 0; f < 4; ++f)
        a[f] = *(const short8v*)(aggF + (size_t)row_a * 128 + f * 32 + klane);
#pragma unroll
    for (int nt = 0; nt < 8; ++nt) {
        f32x4 acc = {0.0f, 0.0f, 0.0f, 0.0f};
#pragma unroll
        for (int f = 0; f < 4; ++f) {
            const short8v b =
                *(const short8v*)(Wf2n + (size_t)(nt * 4 + f) * 512 + lane * 8);
            acc = __builtin_amdgcn_mfma_f32_16x16x32_bf16(a[f], b, acc, 0, 0, 0);
        }
        const int col = nt * 16 + (lane & 15);
        const int r0 = row_base + ((lane >> 4) << 2);
        float lsum = 0.0f, lsq = 0.0f;
#pragma unroll
        for (int r = 0; r < 4; ++r) {
            const size_t o = (size_t)(r0 + r) * 128 + col;
            float v = selu_f(acc[r] + bn2[col] + bf2f(Uf2[o])) + outp[o];
            outp[o] = v;
            lsum += v; lsq += v * v;
        }
        atomicAdd(&s_sum[nt * 16 + (lane & 15)], lsum);
        atomicAdd(&s_sq[nt * 16 + (lane & 15)], lsq);
    }
    __syncthreads();
    if (tid < 128) {
        atomicAdd(&stats[tid], s_sum[tid]);
        atomicAdd(&stats[128 + tid], s_sq[tid]);
    }
}

// ---------------------------------------------------------------------------
// BN normalize + SELU, in place on d_out.
// ---------------------------------------------------------------------------
__global__ __launch_bounds__(256) void bn_kernel(
    float* __restrict__ out, const float* __restrict__ stats,
    const float* __restrict__ gamma, const float* __restrict__ beta, int Nn) {
    const int i = blockIdx.x * blockDim.x + threadIdx.x;
    const int c = i & 127;
    const float invn = 1.0f / (float)Nn;
    float mu = stats[c] * invn;
    float var = stats[128 + c] * invn - mu * mu;
    float r = rsqrtf(var + 1e-5f);
    float v = (out[i] - mu) * r * gamma[c] + beta[c];
    out[i] = selu_f(v);
}

// ---------------------------------------------------------------------------
extern "C" void kernel_launch(void* const* d_in, const int* in_sizes, int n_in,
                              void* d_out, int out_size, void* d_ws, size_t ws_size,
                              hipStream_t stream) {
    const float* x     = (const float*)d_in[0];
    const float* pos_c = (const float*)d_in[1];
    const float* pos_f = (const float*)d_in[2];
    const int*   ei_c  = (const int*)d_in[3];
    const int*   ei_f  = (const int*)d_in[4];
    const float* We1 = (const float*)d_in[5];
    const float* be1 = (const float*)d_in[6];
    const float* Wn1 = (const float*)d_in[7];
    const float* bn1 = (const float*)d_in[8];
    const float* We2 = (const float*)d_in[9];
    const float* be2 = (const float*)d_in[10];
    const float* Wn2 = (const float*)d_in[11];
    const float* bn2 = (const float*)d_in[12];
    const float* WeS = (const float*)d_in[13];
    const float* beS = (const float*)d_in[14];
    const float* WnS = (const float*)d_in[15];
    const float* bnS = (const float*)d_in[16];
    const float* gamma = (const float*)d_in[17];
    const float* beta  = (const float*)d_in[18];

    char* w = (char*)d_ws;
    size_t o = 0;
    auto alloc = [&](size_t bytes) { void* p = w + o; o += (bytes + 255) & ~(size_t)255; return p; };
    float4*   meta    = (float4*)alloc((size_t)NF * 2 * sizeof(float4));
    ushort_t* RA      = (ushort_t*)alloc((size_t)NC * 512 * 2);   // also RE (aliased)
    ushort_t* Uf      = (ushort_t*)alloc((size_t)NF * 128 * 2);   // reused
    ushort_t* aggF    = (ushort_t*)alloc((size_t)NF * 128 * 2);   // reused
    ushort_t* agg1b   = (ushort_t*)alloc((size_t)NC * 64 * 2);
    ushort_t* xb      = (ushort_t*)alloc((size_t)NC * 128 * 2);
    ushort_t* WfA     = (ushort_t*)alloc(65536 * 2);
    ushort_t* WfE     = (ushort_t*)alloc(24576 * 2);
    ushort_t* WfSn    = (ushort_t*)alloc(16384 * 2);
    ushort_t* Wf1n    = (ushort_t*)alloc(12288 * 2);
    ushort_t* Wf2n    = (ushort_t*)alloc(16384 * 2);
    int*   cntF  = (int*)alloc((size_t)NF * sizeof(int));
    int*   baseF = (int*)alloc((size_t)(NF + 1) * sizeof(int));
    int*   cursF = (int*)alloc((size_t)NF * sizeof(int));
    int*   srtF  = (int*)alloc((size_t)EF * sizeof(int));
    int*   cntC  = (int*)alloc((size_t)NC * sizeof(int));
    int*   baseC = (int*)alloc((size_t)(NC + 1) * sizeof(int));
    int*   cursC = (int*)alloc((size_t)NC * sizeof(int));
    int*   srtC  = (int*)alloc((size_t)EC * sizeof(int));
    int*   cntG  = (int*)alloc((size_t)NCELL * sizeof(int));
    int*   baseG = (int*)alloc((size_t)(NCELL + 1) * sizeof(int));
    int*   cursG = (int*)alloc((size_t)NCELL * sizeof(int));
    float4* grecs = (float4*)alloc((size_t)NC * sizeof(float4));
    float* stats = (float*)alloc(256 * sizeof(float));
    ushort_t* RE = RA;               // RA dead once nodeSD starts
    float* outp = (float*)d_out;

    // 1. prep
    constexpr int PREP_TOTAL = NC * 128 + 65536 + 24576 + 16384 + 12288 + 16384
                             + NF + NC + NCELL + 256;
    prep_kernel<<<(PREP_TOTAL + 255) / 256, 256, 0, stream>>>(
        x, xb, WeS, WnS, We1, We2, Wn2, Wn1,
        WfA, WfE, WfSn, Wf1n, Wf2n, cntF, cntC, cntG, stats);

    // 2-4. merged counting sorts
    constexpr int SORT_ITEMS = EF + EC + NC;
    hist3_kernel<<<(SORT_ITEMS + 255) / 256, 256, 0, stream>>>(
        ei_f, ei_c, pos_c, cntF, cntC, cntG);
    scan3_kernel<<<3, 1024, 0, stream>>>(
        cntF, baseF, cursF, cntC, baseC, cursC, cntG, baseG, cursG);
    scatter3_kernel<<<(SORT_ITEMS + 255) / 256, 256, 0, stream>>>(
        ei_f, ei_c, pos_c, cursF, srtF, cursC, srtC, cursG, grecs);

    // 5. RA GEMM (bf16 out) + kNN
    gemmA_knn_kernel<<<768, 256, 0, stream>>>(
        xb, WfA, RA, pos_f, grecs, baseG, meta);

    // 6. aggS: block-per-node fine skip agg + Uf_S + coarse agg1
    agg_kernel<512, true><<<NF + NC, 256, 0, stream>>>(
        RA, meta, baseF, srtF, beS, aggF, Uf, baseC, srtC, be1, agg1b);

    // 7. nodeS (x_skip -> d_out) + node1 + fused gemmE (RE)
    nodeSD_kernel<<<320, 256, 0, stream>>>(
        aggF, WfSn, bnS, Uf, outp, xb, agg1b, Wf1n, bn1, WfE, RE);

    // 8. aggH: block-per-node fine mpl2 agg + Uf_2
    agg_kernel<384, false><<<NF, 256, 0, stream>>>(
        RE, meta, baseF, srtF, be2, aggF, Uf,
        nullptr, nullptr, nullptr, nullptr);

    // 9. nodeH: final MLP + residual + BN stats
    nodeH_kernel<<<256, 256, 0, stream>>>(aggF, Wf2n, bn2, Uf, outp, stats);

    // 10. BN + SELU
    bn_kernel<<<NF * 128 / 256, 256, 0, stream>>>(outp, stats, gamma, beta, NF);
}

// Round 11
// 209.094 us; speedup vs baseline: 1.1270x; 1.1270x over previous
//
#include <hip/hip_runtime.h>

// ---------------------------------------------------------------------------
// Res_up block, round 11: round 10 with agg rewritten as wave-per-node +
// unroll-4 batched gathers (12 independent loads in flight), no LDS reduce,
// 32-bit gather offsets. Everything else unchanged.
// 10 dispatches.
// Sizes fixed: Nc=4096, Nf=16384, Ec=65536, Ef=262144, Cin=128, Ch=64, Co=128.
// ---------------------------------------------------------------------------

#define SELU_SCALE 1.0507009873554805f
#define SELU_ALPHA 1.6732632423543772f

static constexpr int NC = 4096, NF = 16384, EC = 65536, EF = 262144;
static constexpr int G = 32, NCELL = G * G;

typedef __attribute__((ext_vector_type(8))) short short8v;
typedef __attribute__((ext_vector_type(4))) float f32x4;
typedef unsigned short ushort_t;
typedef unsigned long long u64;

__device__ __forceinline__ float selu_f(float x) {
    return x > 0.0f ? SELU_SCALE * x
                    : SELU_SCALE * SELU_ALPHA * (__expf(x) - 1.0f);
}
__device__ __forceinline__ ushort_t f2bf(float f) {
    unsigned u = __float_as_uint(f);
    u += 0x7FFFu + ((u >> 16) & 1u);
    return (ushort_t)(u >> 16);
}
__device__ __forceinline__ float bf2f(ushort_t u) {
    return __uint_as_float(((unsigned)u) << 16);
}
__device__ __forceinline__ int cell_of(float2 p) {
    int cx = (int)(p.x * (float)G); cx = cx > G - 1 ? G - 1 : cx;
    int cy = (int)(p.y * (float)G); cy = cy > G - 1 ? G - 1 : cy;
    return cy * G + cx;
}
__device__ __forceinline__ void ins3(u64& a0, u64& a1, u64& a2, u64 v) {
    if (v < a2) {
        if (v < a1) {
            a2 = a1;
            if (v < a0) { a1 = a0; a0 = v; } else a1 = v;
        } else a2 = v;
    }
}

// ---------------------------------------------------------------------------
// Fragment-major weight writer: Wf[(ntile*KC+kc)*512 + lane*8 + e] = W[k][col]
// ---------------------------------------------------------------------------
template <int K, typename F>
__device__ __forceinline__ void wfrag(F getw, ushort_t* __restrict__ dst, int idx) {
    constexpr int KC = K / 32;
    const int f = idx >> 9;
    const int r = idx & 511;
    const int lane = r >> 3;
    const int e = r & 7;
    const int ntile = f / KC;
    const int kc = f - ntile * KC;
    const int k = kc * 32 + ((lane >> 4) << 3) + e;
    const int col = ntile * 16 + (lane & 15);
    dst[idx] = f2bf(getw(k, col));
}

// ---------------------------------------------------------------------------
// prep: x->bf16, 5 weight-frag buffers, zero cnt/stats.
// ---------------------------------------------------------------------------
__global__ __launch_bounds__(256) void prep_kernel(
    const float* __restrict__ x, ushort_t* __restrict__ xb,
    const float* __restrict__ WeS, const float* __restrict__ WnS,
    const float* __restrict__ We1, const float* __restrict__ We2,
    const float* __restrict__ Wn2, const float* __restrict__ Wn1,
    ushort_t* __restrict__ WfA, ushort_t* __restrict__ WfE,
    ushort_t* __restrict__ WfSn, ushort_t* __restrict__ Wf1n,
    ushort_t* __restrict__ Wf2n,
    int* __restrict__ cntF, int* __restrict__ cntC, int* __restrict__ cntG,
    float* __restrict__ stats) {
    int i = blockIdx.x * 256 + threadIdx.x;
    if (i < NC * 128) { xb[i] = f2bf(x[i]); return; }
    i -= NC * 128;
    if (i < 65536) {   // RA weights: K=128, N=512
        wfrag<128>([&](int k, int j) {
            return j < 128 ? WeS[k * 128 + j]
                 : j < 256 ? WeS[(128 + k) * 128 + (j - 128)]
                 : j < 384 ? WnS[k * 128 + (j - 256)]
                 : j < 448 ? We1[k * 64 + (j - 384)]
                           : We1[(128 + k) * 64 + (j - 448)];
        }, WfA, i);
        return;
    }
    i -= 65536;
    if (i < 24576) {   // RE weights: K=64, N=384
        wfrag<64>([&](int k, int j) {
            return j < 128 ? We2[k * 128 + j]
                 : j < 256 ? We2[(64 + k) * 128 + (j - 128)]
                           : Wn2[k * 128 + (j - 256)];
        }, WfE, i);
        return;
    }
    i -= 24576;
    if (i < 16384) {   // nodeS: WnS bottom half, K=128, N=128
        wfrag<128>([&](int k, int j) { return WnS[(128 + k) * 128 + j]; }, WfSn, i);
        return;
    }
    i -= 16384;
    if (i < 12288) {   // node1: full Wn1, K=192, N=64
        wfrag<192>([&](int k, int j) { return Wn1[k * 64 + j]; }, Wf1n, i);
        return;
    }
    i -= 12288;
    if (i < 16384) {   // nodeH: Wn2 bottom, K=128, N=128
        wfrag<128>([&](int k, int j) { return Wn2[(64 + k) * 128 + j]; }, Wf2n, i);
        return;
    }
    i -= 16384;
    if (i < NF) { cntF[i] = 0; return; }
    i -= NF;
    if (i < NC) { cntC[i] = 0; return; }
    i -= NC;
    if (i < NCELL) { cntG[i] = 0; return; }
    i -= NCELL;
    if (i < 256) { stats[i] = 0.0f; return; }
}

// ---------------------------------------------------------------------------
// merged histogram / scan / scatter for {fine edges, coarse edges, grid cells}
// ---------------------------------------------------------------------------
__global__ __launch_bounds__(256) void hist3_kernel(
    const int* __restrict__ ei_f, const int* __restrict__ ei_c,
    const float* __restrict__ pos_c,
    int* __restrict__ cntF, int* __restrict__ cntC, int* __restrict__ cntG) {
    int i = blockIdx.x * 256 + threadIdx.x;
    if (i < EF) { atomicAdd(&cntF[ei_f[EF + i]], 1); return; }
    i -= EF;
    if (i < EC) { atomicAdd(&cntC[ei_c[EC + i]], 1); return; }
    i -= EC;
    if (i < NC) {
        float2 p = ((const float2*)pos_c)[i];
        atomicAdd(&cntG[cell_of(p)], 1);
    }
}

__global__ __launch_bounds__(1024) void scan3_kernel(
    int* __restrict__ cntF, int* __restrict__ baseF, int* __restrict__ cursF,
    int* __restrict__ cntC, int* __restrict__ baseC, int* __restrict__ cursC,
    int* __restrict__ cntG, int* __restrict__ baseG, int* __restrict__ cursG) {
    const int* cnt; int* base; int* curs; int n;
    if (blockIdx.x == 0)      { cnt = cntF; base = baseF; curs = cursF; n = NF; }
    else if (blockIdx.x == 1) { cnt = cntC; base = baseC; curs = cursC; n = NC; }
    else                      { cnt = cntG; base = baseG; curs = cursG; n = NCELL; }
    const int IT = n >> 10;
    __shared__ int part[1024];
    const int t = threadIdx.x;
    int loc[16];
    int s = 0;
#pragma unroll
    for (int i = 0; i < 16; ++i) {
        int v = (i < IT) ? cnt[t * IT + i] : 0;
        loc[i] = v; s += v;
    }
    part[t] = s;
    __syncthreads();
    for (int off = 1; off < 1024; off <<= 1) {
        int v = part[t];
        int u = (t >= off) ? part[t - off] : 0;
        __syncthreads();
        part[t] = v + u;
        __syncthreads();
    }
    int ex = (t == 0) ? 0 : part[t - 1];
#pragma unroll
    for (int i = 0; i < 16; ++i) {
        if (i < IT) {
            base[t * IT + i] = ex;
            curs[t * IT + i] = ex;
            ex += loc[i];
        }
    }
    if (t == 1023) base[n] = ex;
}

__global__ __launch_bounds__(256) void scatter3_kernel(
    const int* __restrict__ ei_f, const int* __restrict__ ei_c,
    const float* __restrict__ pos_c,
    int* __restrict__ cursF, int* __restrict__ srtF,
    int* __restrict__ cursC, int* __restrict__ srtC,
    int* __restrict__ cursG, float4* __restrict__ grecs) {
    int i = blockIdx.x * 256 + threadIdx.x;
    if (i < EF) {
        int pos = atomicAdd(&cursF[ei_f[EF + i]], 1);
        srtF[pos] = ei_f[i];
        return;
    }
    i -= EF;
    if (i < EC) {
        int pos = atomicAdd(&cursC[ei_c[EC + i]], 1);
        srtC[pos] = ei_c[i];
        return;
    }
    i -= EC;
    if (i < NC) {
        float2 p = ((const float2*)pos_c)[i];
        int pos = atomicAdd(&cursG[cell_of(p)], 1);
        float4 rec;
        rec.x = p.x; rec.y = p.y; rec.z = __int_as_float(i); rec.w = 0.0f;
        grecs[pos] = rec;
    }
}

// ---------------------------------------------------------------------------
// Fused: blocks 0..255 = RA GEMM (4096x512x128, bf16 out);
// blocks 256..767 = grid-kNN, 8 lanes per fine point.
// meta[2t] = idx bits (as float), meta[2t+1] = weights.
// ---------------------------------------------------------------------------
__global__ __launch_bounds__(256) void gemmA_knn_kernel(
    const ushort_t* __restrict__ xb, const ushort_t* __restrict__ WfA,
    ushort_t* __restrict__ RA,
    const float* __restrict__ pos_f, const float4* __restrict__ grecs,
    const int* __restrict__ baseG, float4* __restrict__ meta) {
    const int bid = blockIdx.x;
    const int tid = threadIdx.x;
    if (bid < 256) {
        const int wid = tid >> 6, lane = tid & 63;
        const int bx = bid >> 2, by = bid & 3;
        const int row_base = bx * 64 + wid * 16;
        const int row_a = row_base + (lane & 15);
        const int klane = (lane >> 4) << 3;
        short8v a[4];
#pragma unroll
        for (int f = 0; f < 4; ++f)
            a[f] = *(const short8v*)(xb + (size_t)row_a * 128 + f * 32 + klane);
#pragma unroll
        for (int nt = 0; nt < 8; ++nt) {
            const int ntg = by * 8 + nt;
            f32x4 acc = {0.0f, 0.0f, 0.0f, 0.0f};
#pragma unroll
            for (int f = 0; f < 4; ++f) {
                const short8v b =
                    *(const short8v*)(WfA + (size_t)(ntg * 4 + f) * 512 + lane * 8);
                acc = __builtin_amdgcn_mfma_f32_16x16x32_bf16(a[f], b, acc, 0, 0, 0);
            }
            const int col = ntg * 16 + (lane & 15);
            const int r0 = row_base + ((lane >> 4) << 2);
#pragma unroll
            for (int r = 0; r < 4; ++r)
                RA[(size_t)(r0 + r) * 512 + col] = f2bf(acc[r]);
        }
    } else {
        const int g8 = (bid - 256) * 256 + tid;    // 131072 = 8 * NF
        const int t = g8 >> 3;
        const int sub = g8 & 7;
        const float2 p = ((const float2*)pos_f)[t];
        int cx = (int)(p.x * (float)G); cx = cx > G - 1 ? G - 1 : cx;
        int cy = (int)(p.y * (float)G); cy = cy > G - 1 ? G - 1 : cy;
        const float h = 1.0f / (float)G;

        u64 b0 = ~0ull, b1 = ~0ull, b2 = ~0ull;

        {
            const int xx0 = cx - 1 < 0 ? 0 : cx - 1;
            const int xx1 = cx + 1 > G - 1 ? G - 1 : cx + 1;
            const int yy0 = cy - 1 < 0 ? 0 : cy - 1;
            const int yy1 = cy + 1 > G - 1 ? G - 1 : cy + 1;
            int rs[3], rl[3];
            int nr = 0;
            for (int yy = yy0; yy <= yy1; ++yy) {
                const int s = baseG[yy * G + xx0];
                const int e = baseG[yy * G + xx1 + 1];
                rs[nr] = s; rl[nr] = e - s; ++nr;
            }
            const int l0 = rl[0];
            const int l01 = l0 + (nr > 1 ? rl[1] : 0);
            const int m = l01 + (nr > 2 ? rl[2] : 0);
            for (int j = sub; j < m; j += 8) {
                int i;
                if (j < l0) i = rs[0] + j;
                else if (j < l01) i = rs[1] + (j - l0);
                else i = rs[2] + (j - l01);
                const float4 q = grecs[i];
                const float dx = p.x - q.x;
                const float dy = p.y - q.y;
                const float d = dx * dx + dy * dy;
                ins3(b0, b1, b2, ((u64)__float_as_uint(d) << 32) |
                                 (u64)__float_as_uint(q.z));
            }
#pragma unroll
            for (int mk = 1; mk <= 4; mk <<= 1) {
                const u64 e0 = __shfl_xor(b0, mk);
                const u64 e1 = __shfl_xor(b1, mk);
                const u64 e2 = __shfl_xor(b2, mk);
                ins3(b0, b1, b2, e0);
                ins3(b0, b1, b2, e1);
                ins3(b0, b1, b2, e2);
            }
        }

        for (int r = 2; r < G; ++r) {
            const float bd = __uint_as_float((unsigned)(b2 >> 32));
            const float lim = (float)(r - 1) * h;
            if (bd < lim * lim) break;
            u64 c0 = ~0ull, c1 = ~0ull, c2 = ~0ull;
            auto scan_cells = [&](int cell0, int cell1, int step) {
                for (int c = cell0; c <= cell1; c += step) {
                    const int s0 = baseG[c], s1 = baseG[c + 1];
                    for (int i = s0; i < s1; ++i) {
                        const float4 q = grecs[i];
                        const float dx = p.x - q.x;
                        const float dy = p.y - q.y;
                        const float d = dx * dx + dy * dy;
                        ins3(c0, c1, c2, ((u64)__float_as_uint(d) << 32) |
                                         (u64)__float_as_uint(q.z));
                    }
                }
            };
            const int side = sub & 3, phase = sub >> 2;
            const int x0 = cx - r < 0 ? 0 : cx - r;
            const int x1 = cx + r > G - 1 ? G - 1 : cx + r;
            const int yi0 = cy - r + 1 < 0 ? 0 : cy - r + 1;
            const int yi1 = cy + r - 1 > G - 1 ? G - 1 : cy + r - 1;
            if (side == 0) {
                if (cy - r >= 0) scan_cells((cy - r) * G + x0 + phase, (cy - r) * G + x1, 2);
            } else if (side == 1) {
                if (cy + r <= G - 1) scan_cells((cy + r) * G + x0 + phase, (cy + r) * G + x1, 2);
            } else if (side == 2) {
                if (cx - r >= 0 && yi0 + phase <= yi1)
                    scan_cells((yi0 + phase) * G + cx - r, yi1 * G + cx - r, 2 * G);
            } else {
                if (cx + r <= G - 1 && yi0 + phase <= yi1)
                    scan_cells((yi0 + phase) * G + cx + r, yi1 * G + cx + r, 2 * G);
            }
#pragma unroll
            for (int mk = 1; mk <= 4; mk <<= 1) {
                const u64 e0 = __shfl_xor(c0, mk);
                const u64 e1 = __shfl_xor(c1, mk);
                const u64 e2 = __shfl_xor(c2, mk);
                ins3(c0, c1, c2, e0);
                ins3(c0, c1, c2, e1);
                ins3(c0, c1, c2, e2);
            }
            ins3(b0, b1, b2, c0);
            ins3(b0, b1, b2, c1);
            ins3(b0, b1, b2, c2);
        }

        if (sub == 0) {
            const float d0 = __uint_as_float((unsigned)(b0 >> 32));
            const float d1 = __uint_as_float((unsigned)(b1 >> 32));
            const float d2 = __uint_as_float((unsigned)(b2 >> 32));
            const float w0 = 1.0f / fmaxf(d0, 1e-16f);
            const float w1 = 1.0f / fmaxf(d1, 1e-16f);
            const float w2 = 1.0f / fmaxf(d2, 1e-16f);
            const float s = 1.0f / (w0 + w1 + w2);
            float4 mi;
            mi.x = __uint_as_float((unsigned)(b0 & 0xffffffffu));
            mi.y = __uint_as_float((unsigned)(b1 & 0xffffffffu));
            mi.z = __uint_as_float((unsigned)(b2 & 0xffffffffu));
            mi.w = 0.0f;
            float4 mw;
            mw.x = w0 * s; mw.y = w1 * s; mw.z = w2 * s; mw.w = 0.0f;
            meta[2 * t] = mi;
            meta[2 * t + 1] = mw;
        }
    }
}

// ---------------------------------------------------------------------------
// agg v3: wave-per-node, edge loop unrolled 4x with batched independent
// gathers (4 srt + 8 meta + 12 R loads in flight), 32-bit gather offsets,
// no LDS, no syncthreads.
// R layout: P at 0..127, Q at 128..255, U at 256..383 (bf16, stride STRIDE).
// DUAL: blocks >= NF/4 handle coarse agg1 (RA cols 384..511, no interp).
// ---------------------------------------------------------------------------
template <int STRIDE, bool DUAL>
__global__ __launch_bounds__(256) void agg_kernel(
    const ushort_t* __restrict__ R, const float4* __restrict__ meta,
    const int* __restrict__ baseF, const int* __restrict__ srtF,
    const float* __restrict__ beF, ushort_t* __restrict__ aggF,
    ushort_t* __restrict__ Uf,
    const int* __restrict__ baseC, const int* __restrict__ srtC,
    const float* __restrict__ beC, ushort_t* __restrict__ aggC) {
    const int bid = blockIdx.x;
    const int wid = threadIdx.x >> 6, lane = threadIdx.x & 63;
    if (!DUAL || bid < NF / 4) {
        const int n = bid * 4 + wid;
        const float4 mi = meta[2 * n];
        const float4 mw = meta[2 * n + 1];
        const unsigned o0 = __float_as_uint(mi.x) * STRIDE + (unsigned)(lane * 2);
        const unsigned o1 = __float_as_uint(mi.y) * STRIDE + (unsigned)(lane * 2);
        const unsigned o2 = __float_as_uint(mi.z) * STRIDE + (unsigned)(lane * 2);
        // Q interp + bias
        const float2 bv = *(const float2*)(beF + lane * 2);
        ushort2 a0 = *(const ushort2*)(R + o0 + 128);
        ushort2 a1 = *(const ushort2*)(R + o1 + 128);
        ushort2 a2 = *(const ushort2*)(R + o2 + 128);
        const float qx = mw.x * bf2f(a0.x) + mw.y * bf2f(a1.x) + mw.z * bf2f(a2.x) + bv.x;
        const float qy = mw.x * bf2f(a0.y) + mw.y * bf2f(a1.y) + mw.z * bf2f(a2.y) + bv.y;
        // U interp -> Uf
        a0 = *(const ushort2*)(R + o0 + 256);
        a1 = *(const ushort2*)(R + o1 + 256);
        a2 = *(const ushort2*)(R + o2 + 256);
        ushort2 uo;
        uo.x = f2bf(mw.x * bf2f(a0.x) + mw.y * bf2f(a1.x) + mw.z * bf2f(a2.x));
        uo.y = f2bf(mw.x * bf2f(a0.y) + mw.y * bf2f(a1.y) + mw.z * bf2f(a2.y));
        *(ushort2*)(Uf + (size_t)n * 128 + lane * 2) = uo;
        // edge loop, unrolled by 4 with batched loads
        const int b0 = baseF[n], b1 = baseF[n + 1];
        const unsigned lo = (unsigned)(lane * 2);
        float ax = 0.0f, ay = 0.0f;
        int e = b0;
        for (; e + 4 <= b1; e += 4) {
            const int s0 = srtF[e], s1 = srtF[e + 1];
            const int s2 = srtF[e + 2], s3 = srtF[e + 3];
            const float4 w0 = meta[2 * s0 + 1], i0v = meta[2 * s0];
            const float4 w1 = meta[2 * s1 + 1], i1v = meta[2 * s1];
            const float4 w2 = meta[2 * s2 + 1], i2v = meta[2 * s2];
            const float4 w3 = meta[2 * s3 + 1], i3v = meta[2 * s3];
            const ushort2 g00 = *(const ushort2*)(R + __float_as_uint(i0v.x) * STRIDE + lo);
            const ushort2 g01 = *(const ushort2*)(R + __float_as_uint(i0v.y) * STRIDE + lo);
            const ushort2 g02 = *(const ushort2*)(R + __float_as_uint(i0v.z) * STRIDE + lo);
            const ushort2 g10 = *(const ushort2*)(R + __float_as_uint(i1v.x) * STRIDE + lo);
            const ushort2 g11 = *(const ushort2*)(R + __float_as_uint(i1v.y) * STRIDE + lo);
            const ushort2 g12 = *(const ushort2*)(R + __float_as_uint(i1v.z) * STRIDE + lo);
            const ushort2 g20 = *(const ushort2*)(R + __float_as_uint(i2v.x) * STRIDE + lo);
            const ushort2 g21 = *(const ushort2*)(R + __float_as_uint(i2v.y) * STRIDE + lo);
            const ushort2 g22 = *(const ushort2*)(R + __float_as_uint(i2v.z) * STRIDE + lo);
            const ushort2 g30 = *(const ushort2*)(R + __float_as_uint(i3v.x) * STRIDE + lo);
            const ushort2 g31 = *(const ushort2*)(R + __float_as_uint(i3v.y) * STRIDE + lo);
            const ushort2 g32 = *(const ushort2*)(R + __float_as_uint(i3v.z) * STRIDE + lo);
            float px, py;
            px = w0.x * bf2f(g00.x) + w0.y * bf2f(g01.x) + w0.z * bf2f(g02.x);
            py = w0.x * bf2f(g00.y) + w0.y * bf2f(g01.y) + w0.z * bf2f(g02.y);
            ax += selu_f(px + qx); ay += selu_f(py + qy);
            px = w1.x * bf2f(g10.x) + w1.y * bf2f(g11.x) + w1.z * bf2f(g12.x);
            py = w1.x * bf2f(g10.y) + w1.y * bf2f(g11.y) + w1.z * bf2f(g12.y);
            ax += selu_f(px + qx); ay += selu_f(py + qy);
            px = w2.x * bf2f(g20.x) + w2.y * bf2f(g21.x) + w2.z * bf2f(g22.x);
            py = w2.x * bf2f(g20.y) + w2.y * bf2f(g21.y) + w2.z * bf2f(g22.y);
            ax += selu_f(px + qx); ay += selu_f(py + qy);
            px = w3.x * bf2f(g30.x) + w3.y * bf2f(g31.x) + w3.z * bf2f(g32.x);
            py = w3.x * bf2f(g30.y) + w3.y * bf2f(g31.y) + w3.z * bf2f(g32.y);
            ax += selu_f(px + qx); ay += selu_f(py + qy);
        }
        for (; e < b1; ++e) {
            const int s = srtF[e];
            const float4 sw = meta[2 * s + 1], si = meta[2 * s];
            const ushort2 p0 = *(const ushort2*)(R + __float_as_uint(si.x) * STRIDE + lo);
            const ushort2 p1 = *(const ushort2*)(R + __float_as_uint(si.y) * STRIDE + lo);
            const ushort2 p2 = *(const ushort2*)(R + __float_as_uint(si.z) * STRIDE + lo);
            const float px = sw.x * bf2f(p0.x) + sw.y * bf2f(p1.x) + sw.z * bf2f(p2.x);
            const float py = sw.x * bf2f(p0.y) + sw.y * bf2f(p1.y) + sw.z * bf2f(p2.y);
            ax += selu_f(px + qx); ay += selu_f(py + qy);
        }
        ushort2 r; r.x = f2bf(ax); r.y = f2bf(ay);
        *(ushort2*)(aggF + (size_t)n * 128 + lane * 2) = r;
    } else {
        const int n = (bid - NF / 4) * 4 + wid;
        const int b0 = baseC[n], b1 = baseC[n + 1];
        const float q = bf2f(R[(unsigned)n * 512u + 448 + lane]) + beC[lane];
        const unsigned lo = 384u + (unsigned)lane;
        float s = 0.0f;
        int e = b0;
        for (; e + 4 <= b1; e += 4) {
            const int s0 = srtC[e], s1 = srtC[e + 1];
            const int s2 = srtC[e + 2], s3 = srtC[e + 3];
            const ushort_t v0 = R[(unsigned)s0 * 512u + lo];
            const ushort_t v1 = R[(unsigned)s1 * 512u + lo];
            const ushort_t v2 = R[(unsigned)s2 * 512u + lo];
            const ushort_t v3 = R[(unsigned)s3 * 512u + lo];
            s += selu_f(bf2f(v0) + q);
            s += selu_f(bf2f(v1) + q);
            s += selu_f(bf2f(v2) + q);
            s += selu_f(bf2f(v3) + q);
        }
        for (; e < b1; ++e)
            s += selu_f(bf2f(R[(unsigned)srtC[e] * 512u + lo]) + q);
        aggC[(size_t)n * 64 + lane] = f2bf(s);
    }
}

// ---------------------------------------------------------------------------
// nodeSD: blocks 0..255: x_skip = selu(aggF@WnS_bot + UfS + bnS) -> outp f32
//         blocks 256..319: h1 = selu(concat(xb,agg1b)@Wn1 + bn1) in LDS,
//                          then RE = h1 @ WfE (fused gemmE) -> RE bf16
// ---------------------------------------------------------------------------
__global__ __launch_bounds__(256) void nodeSD_kernel(
    const ushort_t* __restrict__ aggF, const ushort_t* __restrict__ WfSn,
    const float* __restrict__ bnS, const ushort_t* __restrict__ UfS,
    float* __restrict__ outp,
    const ushort_t* __restrict__ xb, const ushort_t* __restrict__ agg1b,
    const ushort_t* __restrict__ Wf1n, const float* __restrict__ bn1,
    const ushort_t* __restrict__ WfE, ushort_t* __restrict__ RE) {
    __shared__ ushort_t h1s[64][72];
    const int tid = threadIdx.x;
    const int wid = tid >> 6, lane = tid & 63;
    const int klane = (lane >> 4) << 3;
    if (blockIdx.x < 256) {
        const int row_base = blockIdx.x * 64 + wid * 16;
        const int row_a = row_base + (lane & 15);
        short8v a[4];
#pragma unroll
        for (int f = 0; f < 4; ++f)
            a[f] = *(const short8v*)(aggF + (size_t)row_a * 128 + f * 32 + klane);
#pragma unroll
        for (int nt = 0; nt < 8; ++nt) {
            f32x4 acc = {0.0f, 0.0f, 0.0f, 0.0f};
#pragma unroll
            for (int f = 0; f < 4; ++f) {
                const short8v b =
                    *(const short8v*)(WfSn + (size_t)(nt * 4 + f) * 512 + lane * 8);
                acc = __builtin_amdgcn_mfma_f32_16x16x32_bf16(a[f], b, acc, 0, 0, 0);
            }
            const int col = nt * 16 + (lane & 15);
            const int r0 = row_base + ((lane >> 4) << 2);
#pragma unroll
            for (int r = 0; r < 4; ++r) {
                const size_t o = (size_t)(r0 + r) * 128 + col;
                outp[o] = selu_f(acc[r] + bnS[col] + bf2f(UfS[o]));
            }
        }
    } else {
        const int row_base = (blockIdx.x - 256) * 64 + wid * 16;
        const int row_a = row_base + (lane & 15);
        short8v a[6];
#pragma unroll
        for (int f = 0; f < 4; ++f)
            a[f] = *(const short8v*)(xb + (size_t)row_a * 128 + f * 32 + klane);
#pragma unroll
        for (int f = 0; f < 2; ++f)
            a[4 + f] = *(const short8v*)(agg1b + (size_t)row_a * 64 + f * 32 + klane);
#pragma unroll
        for (int nt = 0; nt < 4; ++nt) {
            f32x4 acc = {0.0f, 0.0f, 0.0f, 0.0f};
#pragma unroll
            for (int f = 0; f < 6; ++f) {
                const short8v b =
                    *(const short8v*)(Wf1n + (size_t)(nt * 6 + f) * 512 + lane * 8);
                acc = __builtin_amdgcn_mfma_f32_16x16x32_bf16(a[f], b, acc, 0, 0, 0);
            }
            const int col = nt * 16 + (lane & 15);
            const int lr0 = wid * 16 + ((lane >> 4) << 2);
#pragma unroll
            for (int r = 0; r < 4; ++r)
                h1s[lr0 + r][col] = f2bf(selu_f(acc[r] + bn1[col]));
        }
        __syncthreads();
        short8v ha[2];
#pragma unroll
        for (int f = 0; f < 2; ++f)
            ha[f] = *(const short8v*)&h1s[wid * 16 + (lane & 15)][f * 32 + klane];
#pragma unroll
        for (int nt = 0; nt < 24; ++nt) {
            f32x4 acc = {0.0f, 0.0f, 0.0f, 0.0f};
#pragma unroll
            for (int f = 0; f < 2; ++f) {
                const short8v b =
                    *(const short8v*)(WfE + (size_t)(nt * 2 + f) * 512 + lane * 8);
                acc = __builtin_amdgcn_mfma_f32_16x16x32_bf16(ha[f], b, acc, 0, 0, 0);
            }
            const int col = nt * 16 + (lane & 15);
            const int r0 = row_base + ((lane >> 4) << 2);
#pragma unroll
            for (int r = 0; r < 4; ++r)
                RE[(size_t)(r0 + r) * 384 + col] = f2bf(acc[r]);
        }
    }
}

// ---------------------------------------------------------------------------
// nodeH: v = selu(aggF@Wn2_bot + Uf2 + bn2) + x_skip; write outp; BN stats.
// ---------------------------------------------------------------------------
__global__ __launch_bounds__(256) void nodeH_kernel(
    const ushort_t* __restrict__ aggF, const ushort_t* __restrict__ Wf2n,
    const float* __restrict__ bn2, const ushort_t* __restrict__ Uf2,
    float* __restrict__ outp, float* __restrict__ stats) {
    __shared__ float s_sum[128], s_sq[128];
    const int tid = threadIdx.x;
    const int wid = tid >> 6, lane = tid & 63;
    const int klane = (lane >> 4) << 3;
    if (tid < 128) { s_sum[tid] = 0.0f; s_sq[tid] = 0.0f; }
    __syncthreads();
    const int row_base = blockIdx.x * 64 + wid * 16;
    const int row_a = row_base + (lane & 15);
    short8v a[4];
#pragma unroll
    for (int f = 0; f < 4; ++f)
        a[f] = *(const short8v*)(aggF + (size_t)row_a * 128 + f * 32 + klane);
#pragma unroll
    for (int nt = 0; nt < 8; ++nt) {
        f32x4 acc = {0.0f, 0.0f, 0.0f, 0.0f};
#pragma unroll
        for (int f = 0; f < 4; ++f) {
            const short8v b =
                *(const short8v*)(Wf2n + (size_t)(nt * 4 + f) * 512 + lane * 8);
            acc = __builtin_amdgcn_mfma_f32_16x16x32_bf16(a[f], b, acc, 0, 0, 0);
        }
        const int col = nt * 16 + (lane & 15);
        const int r0 = row_base + ((lane >> 4) << 2);
        float lsum = 0.0f, lsq = 0.0f;
#pragma unroll
        for (int r = 0; r < 4; ++r) {
            const size_t o = (size_t)(r0 + r) * 128 + col;
            float v = selu_f(acc[r] + bn2[col] + bf2f(Uf2[o])) + outp[o];
            outp[o] = v;
            lsum += v; lsq += v * v;
        }
        atomicAdd(&s_sum[nt * 16 + (lane & 15)], lsum);
        atomicAdd(&s_sq[nt * 16 + (lane & 15)], lsq);
    }
    __syncthreads();
    if (tid < 128) {
        atomicAdd(&stats[tid], s_sum[tid]);
        atomicAdd(&stats[128 + tid], s_sq[tid]);
    }
}

// ---------------------------------------------------------------------------
// BN normalize + SELU, in place on d_out.
// ---------------------------------------------------------------------------
__global__ __launch_bounds__(256) void bn_kernel(
    float* __restrict__ out, const float* __restrict__ stats,
    const float* __restrict__ gamma, const float* __restrict__ beta, int Nn) {
    const int i = blockIdx.x * blockDim.x + threadIdx.x;
    const int c = i & 127;
    const float invn = 1.0f / (float)Nn;
    float mu = stats[c] * invn;
    float var = stats[128 + c] * invn - mu * mu;
    float r = rsqrtf(var + 1e-5f);
    float v = (out[i] - mu) * r * gamma[c] + beta[c];
    out[i] = selu_f(v);
}

// ---------------------------------------------------------------------------
extern "C" void kernel_launch(void* const* d_in, const int* in_sizes, int n_in,
                              void* d_out, int out_size, void* d_ws, size_t ws_size,
                              hipStream_t stream) {
    const float* x     = (const float*)d_in[0];
    const float* pos_c = (const float*)d_in[1];
    const float* pos_f = (const float*)d_in[2];
    const int*   ei_c  = (const int*)d_in[3];
    const int*   ei_f  = (const int*)d_in[4];
    const float* We1 = (const float*)d_in[5];
    const float* be1 = (const float*)d_in[6];
    const float* Wn1 = (const float*)d_in[7];
    const float* bn1 = (const float*)d_in[8];
    const float* We2 = (const float*)d_in[9];
    const float* be2 = (const float*)d_in[10];
    const float* Wn2 = (const float*)d_in[11];
    const float* bn2 = (const float*)d_in[12];
    const float* WeS = (const float*)d_in[13];
    const float* beS = (const float*)d_in[14];
    const float* WnS = (const float*)d_in[15];
    const float* bnS = (const float*)d_in[16];
    const float* gamma = (const float*)d_in[17];
    const float* beta  = (const float*)d_in[18];

    char* w = (char*)d_ws;
    size_t o = 0;
    auto alloc = [&](size_t bytes) { void* p = w + o; o += (bytes + 255) & ~(size_t)255; return p; };
    float4*   meta    = (float4*)alloc((size_t)NF * 2 * sizeof(float4));
    ushort_t* RA      = (ushort_t*)alloc((size_t)NC * 512 * 2);   // also RE (aliased)
    ushort_t* Uf      = (ushort_t*)alloc((size_t)NF * 128 * 2);   // reused
    ushort_t* aggF    = (ushort_t*)alloc((size_t)NF * 128 * 2);   // reused
    ushort_t* agg1b   = (ushort_t*)alloc((size_t)NC * 64 * 2);
    ushort_t* xb      = (ushort_t*)alloc((size_t)NC * 128 * 2);
    ushort_t* WfA     = (ushort_t*)alloc(65536 * 2);
    ushort_t* WfE     = (ushort_t*)alloc(24576 * 2);
    ushort_t* WfSn    = (ushort_t*)alloc(16384 * 2);
    ushort_t* Wf1n    = (ushort_t*)alloc(12288 * 2);
    ushort_t* Wf2n    = (ushort_t*)alloc(16384 * 2);
    int*   cntF  = (int*)alloc((size_t)NF * sizeof(int));
    int*   baseF = (int*)alloc((size_t)(NF + 1) * sizeof(int));
    int*   cursF = (int*)alloc((size_t)NF * sizeof(int));
    int*   srtF  = (int*)alloc((size_t)EF * sizeof(int));
    int*   cntC  = (int*)alloc((size_t)NC * sizeof(int));
    int*   baseC = (int*)alloc((size_t)(NC + 1) * sizeof(int));
    int*   cursC = (int*)alloc((size_t)NC * sizeof(int));
    int*   srtC  = (int*)alloc((size_t)EC * sizeof(int));
    int*   cntG  = (int*)alloc((size_t)NCELL * sizeof(int));
    int*   baseG = (int*)alloc((size_t)(NCELL + 1) * sizeof(int));
    int*   cursG = (int*)alloc((size_t)NCELL * sizeof(int));
    float4* grecs = (float4*)alloc((size_t)NC * sizeof(float4));
    float* stats = (float*)alloc(256 * sizeof(float));
    ushort_t* RE = RA;               // RA dead once nodeSD starts
    float* outp = (float*)d_out;

    // 1. prep
    constexpr int PREP_TOTAL = NC * 128 + 65536 + 24576 + 16384 + 12288 + 16384
                             + NF + NC + NCELL + 256;
    prep_kernel<<<(PREP_TOTAL + 255) / 256, 256, 0, stream>>>(
        x, xb, WeS, WnS, We1, We2, Wn2, Wn1,
        WfA, WfE, WfSn, Wf1n, Wf2n, cntF, cntC, cntG, stats);

    // 2-4. merged counting sorts
    constexpr int SORT_ITEMS = EF + EC + NC;
    hist3_kernel<<<(SORT_ITEMS + 255) / 256, 256, 0, stream>>>(
        ei_f, ei_c, pos_c, cntF, cntC, cntG);
    scan3_kernel<<<3, 1024, 0, stream>>>(
        cntF, baseF, cursF, cntC, baseC, cursC, cntG, baseG, cursG);
    scatter3_kernel<<<(SORT_ITEMS + 255) / 256, 256, 0, stream>>>(
        ei_f, ei_c, pos_c, cursF, srtF, cursC, srtC, cursG, grecs);

    // 5. RA GEMM (bf16 out) + kNN
    gemmA_knn_kernel<<<768, 256, 0, stream>>>(
        xb, WfA, RA, pos_f, grecs, baseG, meta);

    // 6. aggS: wave-per-node fine skip agg + Uf_S + coarse agg1
    agg_kernel<512, true><<<NF / 4 + NC / 4, 256, 0, stream>>>(
        RA, meta, baseF, srtF, beS, aggF, Uf, baseC, srtC, be1, agg1b);

    // 7. nodeS (x_skip -> d_out) + node1 + fused gemmE (RE)
    nodeSD_kernel<<<320, 256, 0, stream>>>(
        aggF, WfSn, bnS, Uf, outp, xb, agg1b, Wf1n, bn1, WfE, RE);

    // 8. aggH: wave-per-node fine mpl2 agg + Uf_2
    agg_kernel<384, false><<<NF / 4, 256, 0, stream>>>(
        RE, meta, baseF, srtF, be2, aggF, Uf,
        nullptr, nullptr, nullptr, nullptr);

    // 9. nodeH: final MLP + residual + BN stats
    nodeH_kernel<<<256, 256, 0, stream>>>(aggF, Wf2n, bn2, Uf, outp, stats);

    // 10. BN + SELU
    bn_kernel<<<NF * 128 / 256, 256, 0, stream>>>(outp, stats, gamma, beta, NF);
}

// Round 12
// 191.426 us; speedup vs baseline: 1.2310x; 1.0923x over previous
//
#include <hip/hip_runtime.h>

// ---------------------------------------------------------------------------
// Res_up block, round 12: round 11 + per-node interpolated P/Q materialized
// once (pf_kernel) so the agg edge loop is 1 srt load + 1 Pf gather per edge
// (was 1 srt + 2 meta + 3 R). 12 dispatches.
// Sizes fixed: Nc=4096, Nf=16384, Ec=65536, Ef=262144, Cin=128, Ch=64, Co=128.
// ---------------------------------------------------------------------------

#define SELU_SCALE 1.0507009873554805f
#define SELU_ALPHA 1.6732632423543772f

static constexpr int NC = 4096, NF = 16384, EC = 65536, EF = 262144;
static constexpr int G = 32, NCELL = G * G;

typedef __attribute__((ext_vector_type(8))) short short8v;
typedef __attribute__((ext_vector_type(4))) float f32x4;
typedef unsigned short ushort_t;
typedef unsigned long long u64;

__device__ __forceinline__ float selu_f(float x) {
    return x > 0.0f ? SELU_SCALE * x
                    : SELU_SCALE * SELU_ALPHA * (__expf(x) - 1.0f);
}
__device__ __forceinline__ ushort_t f2bf(float f) {
    unsigned u = __float_as_uint(f);
    u += 0x7FFFu + ((u >> 16) & 1u);
    return (ushort_t)(u >> 16);
}
__device__ __forceinline__ float bf2f(ushort_t u) {
    return __uint_as_float(((unsigned)u) << 16);
}
__device__ __forceinline__ int cell_of(float2 p) {
    int cx = (int)(p.x * (float)G); cx = cx > G - 1 ? G - 1 : cx;
    int cy = (int)(p.y * (float)G); cy = cy > G - 1 ? G - 1 : cy;
    return cy * G + cx;
}
__device__ __forceinline__ void ins3(u64& a0, u64& a1, u64& a2, u64 v) {
    if (v < a2) {
        if (v < a1) {
            a2 = a1;
            if (v < a0) { a1 = a0; a0 = v; } else a1 = v;
        } else a2 = v;
    }
}

// ---------------------------------------------------------------------------
// Fragment-major weight writer: Wf[(ntile*KC+kc)*512 + lane*8 + e] = W[k][col]
// ---------------------------------------------------------------------------
template <int K, typename F>
__device__ __forceinline__ void wfrag(F getw, ushort_t* __restrict__ dst, int idx) {
    constexpr int KC = K / 32;
    const int f = idx >> 9;
    const int r = idx & 511;
    const int lane = r >> 3;
    const int e = r & 7;
    const int ntile = f / KC;
    const int kc = f - ntile * KC;
    const int k = kc * 32 + ((lane >> 4) << 3) + e;
    const int col = ntile * 16 + (lane & 15);
    dst[idx] = f2bf(getw(k, col));
}

// ---------------------------------------------------------------------------
// prep: x->bf16, 5 weight-frag buffers, zero cnt/stats.
// ---------------------------------------------------------------------------
__global__ __launch_bounds__(256) void prep_kernel(
    const float* __restrict__ x, ushort_t* __restrict__ xb,
    const float* __restrict__ WeS, const float* __restrict__ WnS,
    const float* __restrict__ We1, const float* __restrict__ We2,
    const float* __restrict__ Wn2, const float* __restrict__ Wn1,
    ushort_t* __restrict__ WfA, ushort_t* __restrict__ WfE,
    ushort_t* __restrict__ WfSn, ushort_t* __restrict__ Wf1n,
    ushort_t* __restrict__ Wf2n,
    int* __restrict__ cntF, int* __restrict__ cntC, int* __restrict__ cntG,
    float* __restrict__ stats) {
    int i = blockIdx.x * 256 + threadIdx.x;
    if (i < NC * 128) { xb[i] = f2bf(x[i]); return; }
    i -= NC * 128;
    if (i < 65536) {   // RA weights: K=128, N=512
        wfrag<128>([&](int k, int j) {
            return j < 128 ? WeS[k * 128 + j]
                 : j < 256 ? WeS[(128 + k) * 128 + (j - 128)]
                 : j < 384 ? WnS[k * 128 + (j - 256)]
                 : j < 448 ? We1[k * 64 + (j - 384)]
                           : We1[(128 + k) * 64 + (j - 448)];
        }, WfA, i);
        return;
    }
    i -= 65536;
    if (i < 24576) {   // RE weights: K=64, N=384
        wfrag<64>([&](int k, int j) {
            return j < 128 ? We2[k * 128 + j]
                 : j < 256 ? We2[(64 + k) * 128 + (j - 128)]
                           : Wn2[k * 128 + (j - 256)];
        }, WfE, i);
        return;
    }
    i -= 24576;
    if (i < 16384) {   // nodeS: WnS bottom half, K=128, N=128
        wfrag<128>([&](int k, int j) { return WnS[(128 + k) * 128 + j]; }, WfSn, i);
        return;
    }
    i -= 16384;
    if (i < 12288) {   // node1: full Wn1, K=192, N=64
        wfrag<192>([&](int k, int j) { return Wn1[k * 64 + j]; }, Wf1n, i);
        return;
    }
    i -= 12288;
    if (i < 16384) {   // nodeH: Wn2 bottom, K=128, N=128
        wfrag<128>([&](int k, int j) { return Wn2[(64 + k) * 128 + j]; }, Wf2n, i);
        return;
    }
    i -= 16384;
    if (i < NF) { cntF[i] = 0; return; }
    i -= NF;
    if (i < NC) { cntC[i] = 0; return; }
    i -= NC;
    if (i < NCELL) { cntG[i] = 0; return; }
    i -= NCELL;
    if (i < 256) { stats[i] = 0.0f; return; }
}

// ---------------------------------------------------------------------------
// merged histogram / scan / scatter for {fine edges, coarse edges, grid cells}
// ---------------------------------------------------------------------------
__global__ __launch_bounds__(256) void hist3_kernel(
    const int* __restrict__ ei_f, const int* __restrict__ ei_c,
    const float* __restrict__ pos_c,
    int* __restrict__ cntF, int* __restrict__ cntC, int* __restrict__ cntG) {
    int i = blockIdx.x * 256 + threadIdx.x;
    if (i < EF) { atomicAdd(&cntF[ei_f[EF + i]], 1); return; }
    i -= EF;
    if (i < EC) { atomicAdd(&cntC[ei_c[EC + i]], 1); return; }
    i -= EC;
    if (i < NC) {
        float2 p = ((const float2*)pos_c)[i];
        atomicAdd(&cntG[cell_of(p)], 1);
    }
}

__global__ __launch_bounds__(1024) void scan3_kernel(
    int* __restrict__ cntF, int* __restrict__ baseF, int* __restrict__ cursF,
    int* __restrict__ cntC, int* __restrict__ baseC, int* __restrict__ cursC,
    int* __restrict__ cntG, int* __restrict__ baseG, int* __restrict__ cursG) {
    const int* cnt; int* base; int* curs; int n;
    if (blockIdx.x == 0)      { cnt = cntF; base = baseF; curs = cursF; n = NF; }
    else if (blockIdx.x == 1) { cnt = cntC; base = baseC; curs = cursC; n = NC; }
    else                      { cnt = cntG; base = baseG; curs = cursG; n = NCELL; }
    const int IT = n >> 10;
    __shared__ int part[1024];
    const int t = threadIdx.x;
    int loc[16];
    int s = 0;
#pragma unroll
    for (int i = 0; i < 16; ++i) {
        int v = (i < IT) ? cnt[t * IT + i] : 0;
        loc[i] = v; s += v;
    }
    part[t] = s;
    __syncthreads();
    for (int off = 1; off < 1024; off <<= 1) {
        int v = part[t];
        int u = (t >= off) ? part[t - off] : 0;
        __syncthreads();
        part[t] = v + u;
        __syncthreads();
    }
    int ex = (t == 0) ? 0 : part[t - 1];
#pragma unroll
    for (int i = 0; i < 16; ++i) {
        if (i < IT) {
            base[t * IT + i] = ex;
            curs[t * IT + i] = ex;
            ex += loc[i];
        }
    }
    if (t == 1023) base[n] = ex;
}

__global__ __launch_bounds__(256) void scatter3_kernel(
    const int* __restrict__ ei_f, const int* __restrict__ ei_c,
    const float* __restrict__ pos_c,
    int* __restrict__ cursF, int* __restrict__ srtF,
    int* __restrict__ cursC, int* __restrict__ srtC,
    int* __restrict__ cursG, float4* __restrict__ grecs) {
    int i = blockIdx.x * 256 + threadIdx.x;
    if (i < EF) {
        int pos = atomicAdd(&cursF[ei_f[EF + i]], 1);
        srtF[pos] = ei_f[i];
        return;
    }
    i -= EF;
    if (i < EC) {
        int pos = atomicAdd(&cursC[ei_c[EC + i]], 1);
        srtC[pos] = ei_c[i];
        return;
    }
    i -= EC;
    if (i < NC) {
        float2 p = ((const float2*)pos_c)[i];
        int pos = atomicAdd(&cursG[cell_of(p)], 1);
        float4 rec;
        rec.x = p.x; rec.y = p.y; rec.z = __int_as_float(i); rec.w = 0.0f;
        grecs[pos] = rec;
    }
}

// ---------------------------------------------------------------------------
// Fused: blocks 0..255 = RA GEMM (4096x512x128, bf16 out);
// blocks 256..767 = grid-kNN, 8 lanes per fine point.
// meta[2t] = idx bits (as float), meta[2t+1] = weights.
// ---------------------------------------------------------------------------
__global__ __launch_bounds__(256) void gemmA_knn_kernel(
    const ushort_t* __restrict__ xb, const ushort_t* __restrict__ WfA,
    ushort_t* __restrict__ RA,
    const float* __restrict__ pos_f, const float4* __restrict__ grecs,
    const int* __restrict__ baseG, float4* __restrict__ meta) {
    const int bid = blockIdx.x;
    const int tid = threadIdx.x;
    if (bid < 256) {
        const int wid = tid >> 6, lane = tid & 63;
        const int bx = bid >> 2, by = bid & 3;
        const int row_base = bx * 64 + wid * 16;
        const int row_a = row_base + (lane & 15);
        const int klane = (lane >> 4) << 3;
        short8v a[4];
#pragma unroll
        for (int f = 0; f < 4; ++f)
            a[f] = *(const short8v*)(xb + (size_t)row_a * 128 + f * 32 + klane);
#pragma unroll
        for (int nt = 0; nt < 8; ++nt) {
            const int ntg = by * 8 + nt;
            f32x4 acc = {0.0f, 0.0f, 0.0f, 0.0f};
#pragma unroll
            for (int f = 0; f < 4; ++f) {
                const short8v b =
                    *(const short8v*)(WfA + (size_t)(ntg * 4 + f) * 512 + lane * 8);
                acc = __builtin_amdgcn_mfma_f32_16x16x32_bf16(a[f], b, acc, 0, 0, 0);
            }
            const int col = ntg * 16 + (lane & 15);
            const int r0 = row_base + ((lane >> 4) << 2);
#pragma unroll
            for (int r = 0; r < 4; ++r)
                RA[(size_t)(r0 + r) * 512 + col] = f2bf(acc[r]);
        }
    } else {
        const int g8 = (bid - 256) * 256 + tid;    // 131072 = 8 * NF
        const int t = g8 >> 3;
        const int sub = g8 & 7;
        const float2 p = ((const float2*)pos_f)[t];
        int cx = (int)(p.x * (float)G); cx = cx > G - 1 ? G - 1 : cx;
        int cy = (int)(p.y * (float)G); cy = cy > G - 1 ? G - 1 : cy;
        const float h = 1.0f / (float)G;

        u64 b0 = ~0ull, b1 = ~0ull, b2 = ~0ull;

        {
            const int xx0 = cx - 1 < 0 ? 0 : cx - 1;
            const int xx1 = cx + 1 > G - 1 ? G - 1 : cx + 1;
            const int yy0 = cy - 1 < 0 ? 0 : cy - 1;
            const int yy1 = cy + 1 > G - 1 ? G - 1 : cy + 1;
            int rs[3], rl[3];
            int nr = 0;
            for (int yy = yy0; yy <= yy1; ++yy) {
                const int s = baseG[yy * G + xx0];
                const int e = baseG[yy * G + xx1 + 1];
                rs[nr] = s; rl[nr] = e - s; ++nr;
            }
            const int l0 = rl[0];
            const int l01 = l0 + (nr > 1 ? rl[1] : 0);
            const int m = l01 + (nr > 2 ? rl[2] : 0);
            for (int j = sub; j < m; j += 8) {
                int i;
                if (j < l0) i = rs[0] + j;
                else if (j < l01) i = rs[1] + (j - l0);
                else i = rs[2] + (j - l01);
                const float4 q = grecs[i];
                const float dx = p.x - q.x;
                const float dy = p.y - q.y;
                const float d = dx * dx + dy * dy;
                ins3(b0, b1, b2, ((u64)__float_as_uint(d) << 32) |
                                 (u64)__float_as_uint(q.z));
            }
#pragma unroll
            for (int mk = 1; mk <= 4; mk <<= 1) {
                const u64 e0 = __shfl_xor(b0, mk);
                const u64 e1 = __shfl_xor(b1, mk);
                const u64 e2 = __shfl_xor(b2, mk);
                ins3(b0, b1, b2, e0);
                ins3(b0, b1, b2, e1);
                ins3(b0, b1, b2, e2);
            }
        }

        for (int r = 2; r < G; ++r) {
            const float bd = __uint_as_float((unsigned)(b2 >> 32));
            const float lim = (float)(r - 1) * h;
            if (bd < lim * lim) break;
            u64 c0 = ~0ull, c1 = ~0ull, c2 = ~0ull;
            auto scan_cells = [&](int cell0, int cell1, int step) {
                for (int c = cell0; c <= cell1; c += step) {
                    const int s0 = baseG[c], s1 = baseG[c + 1];
                    for (int i = s0; i < s1; ++i) {
                        const float4 q = grecs[i];
                        const float dx = p.x - q.x;
                        const float dy = p.y - q.y;
                        const float d = dx * dx + dy * dy;
                        ins3(c0, c1, c2, ((u64)__float_as_uint(d) << 32) |
                                         (u64)__float_as_uint(q.z));
                    }
                }
            };
            const int side = sub & 3, phase = sub >> 2;
            const int x0 = cx - r < 0 ? 0 : cx - r;
            const int x1 = cx + r > G - 1 ? G - 1 : cx + r;
            const int yi0 = cy - r + 1 < 0 ? 0 : cy - r + 1;
            const int yi1 = cy + r - 1 > G - 1 ? G - 1 : cy + r - 1;
            if (side == 0) {
                if (cy - r >= 0) scan_cells((cy - r) * G + x0 + phase, (cy - r) * G + x1, 2);
            } else if (side == 1) {
                if (cy + r <= G - 1) scan_cells((cy + r) * G + x0 + phase, (cy + r) * G + x1, 2);
            } else if (side == 2) {
                if (cx - r >= 0 && yi0 + phase <= yi1)
                    scan_cells((yi0 + phase) * G + cx - r, yi1 * G + cx - r, 2 * G);
            } else {
                if (cx + r <= G - 1 && yi0 + phase <= yi1)
                    scan_cells((yi0 + phase) * G + cx + r, yi1 * G + cx + r, 2 * G);
            }
#pragma unroll
            for (int mk = 1; mk <= 4; mk <<= 1) {
                const u64 e0 = __shfl_xor(c0, mk);
                const u64 e1 = __shfl_xor(c1, mk);
                const u64 e2 = __shfl_xor(c2, mk);
                ins3(c0, c1, c2, e0);
                ins3(c0, c1, c2, e1);
                ins3(c0, c1, c2, e2);
            }
            ins3(b0, b1, b2, c0);
            ins3(b0, b1, b2, c1);
            ins3(b0, b1, b2, c2);
        }

        if (sub == 0) {
            const float d0 = __uint_as_float((unsigned)(b0 >> 32));
            const float d1 = __uint_as_float((unsigned)(b1 >> 32));
            const float d2 = __uint_as_float((unsigned)(b2 >> 32));
            const float w0 = 1.0f / fmaxf(d0, 1e-16f);
            const float w1 = 1.0f / fmaxf(d1, 1e-16f);
            const float w2 = 1.0f / fmaxf(d2, 1e-16f);
            const float s = 1.0f / (w0 + w1 + w2);
            float4 mi;
            mi.x = __uint_as_float((unsigned)(b0 & 0xffffffffu));
            mi.y = __uint_as_float((unsigned)(b1 & 0xffffffffu));
            mi.z = __uint_as_float((unsigned)(b2 & 0xffffffffu));
            mi.w = 0.0f;
            float4 mw;
            mw.x = w0 * s; mw.y = w1 * s; mw.z = w2 * s; mw.w = 0.0f;
            meta[2 * t] = mi;
            meta[2 * t + 1] = mw;
        }
    }
}

// ---------------------------------------------------------------------------
// pf: materialize per-fine-node interpolations from coarse R:
//   Pf[n] = interp(P cols 0..127)          (bf16)
//   Qf[n] = interp(Q cols 128..255) + be   (bf16)
//   Uf[n] = interp(U cols 256..383)        (bf16)
// One wave per node; 9 independent ushort2 gathers per lane.
// ---------------------------------------------------------------------------
template <int STRIDE>
__global__ __launch_bounds__(256) void pf_kernel(
    const ushort_t* __restrict__ R, const float4* __restrict__ meta,
    const float* __restrict__ be, ushort_t* __restrict__ Pf,
    ushort_t* __restrict__ Qf, ushort_t* __restrict__ Uf) {
    const int gid = blockIdx.x * 256 + threadIdx.x;
    const int n = gid >> 6, lane = gid & 63;
    const float4 mi = meta[2 * n];
    const float4 mw = meta[2 * n + 1];
    const unsigned lo = (unsigned)(lane * 2);
    const unsigned o0 = __float_as_uint(mi.x) * STRIDE + lo;
    const unsigned o1 = __float_as_uint(mi.y) * STRIDE + lo;
    const unsigned o2 = __float_as_uint(mi.z) * STRIDE + lo;
    const ushort2 p0 = *(const ushort2*)(R + o0);
    const ushort2 p1 = *(const ushort2*)(R + o1);
    const ushort2 p2 = *(const ushort2*)(R + o2);
    const ushort2 q0 = *(const ushort2*)(R + o0 + 128);
    const ushort2 q1 = *(const ushort2*)(R + o1 + 128);
    const ushort2 q2 = *(const ushort2*)(R + o2 + 128);
    const ushort2 u0 = *(const ushort2*)(R + o0 + 256);
    const ushort2 u1 = *(const ushort2*)(R + o1 + 256);
    const ushort2 u2 = *(const ushort2*)(R + o2 + 256);
    const float2 bv = *(const float2*)(be + lane * 2);
    ushort2 po, qo, uo;
    po.x = f2bf(mw.x * bf2f(p0.x) + mw.y * bf2f(p1.x) + mw.z * bf2f(p2.x));
    po.y = f2bf(mw.x * bf2f(p0.y) + mw.y * bf2f(p1.y) + mw.z * bf2f(p2.y));
    qo.x = f2bf(mw.x * bf2f(q0.x) + mw.y * bf2f(q1.x) + mw.z * bf2f(q2.x) + bv.x);
    qo.y = f2bf(mw.x * bf2f(q0.y) + mw.y * bf2f(q1.y) + mw.z * bf2f(q2.y) + bv.y);
    uo.x = f2bf(mw.x * bf2f(u0.x) + mw.y * bf2f(u1.x) + mw.z * bf2f(u2.x));
    uo.y = f2bf(mw.x * bf2f(u0.y) + mw.y * bf2f(u1.y) + mw.z * bf2f(u2.y));
    *(ushort2*)(Pf + (size_t)n * 128 + lo) = po;
    *(ushort2*)(Qf + (size_t)n * 128 + lo) = qo;
    *(ushort2*)(Uf + (size_t)n * 128 + lo) = uo;
}

// ---------------------------------------------------------------------------
// agg v4: wave-per-node; per edge = 1 uniform srt load + 1 Pf gather.
// Unroll 8. Qf already includes bias.
// DUAL: blocks >= NF/4 handle coarse agg1 (RA cols 384..511, no interp).
// ---------------------------------------------------------------------------
template <bool DUAL>
__global__ __launch_bounds__(256) void agg_kernel(
    const ushort_t* __restrict__ Pf, const ushort_t* __restrict__ Qf,
    const int* __restrict__ baseF, const int* __restrict__ srtF,
    ushort_t* __restrict__ aggF,
    const ushort_t* __restrict__ R, const int* __restrict__ baseC,
    const int* __restrict__ srtC, const float* __restrict__ beC,
    ushort_t* __restrict__ aggC) {
    const int bid = blockIdx.x;
    const int wid = threadIdx.x >> 6, lane = threadIdx.x & 63;
    const unsigned lo = (unsigned)(lane * 2);
    if (!DUAL || bid < NF / 4) {
        const int n = bid * 4 + wid;
        const ushort2 qv = *(const ushort2*)(Qf + (size_t)n * 128 + lo);
        const float qx = bf2f(qv.x), qy = bf2f(qv.y);
        const int b0 = baseF[n], b1 = baseF[n + 1];
        float ax = 0.0f, ay = 0.0f;
        int e = b0;
        for (; e + 8 <= b1; e += 8) {
            int s[8];
#pragma unroll
            for (int j = 0; j < 8; ++j) s[j] = srtF[e + j];
            ushort2 g[8];
#pragma unroll
            for (int j = 0; j < 8; ++j)
                g[j] = *(const ushort2*)(Pf + (unsigned)s[j] * 128u + lo);
#pragma unroll
            for (int j = 0; j < 8; ++j) {
                ax += selu_f(bf2f(g[j].x) + qx);
                ay += selu_f(bf2f(g[j].y) + qy);
            }
        }
        if (e < b1) {
            int s[8];
            ushort2 g[8];
            const int m = b1 - e;
#pragma unroll
            for (int j = 0; j < 8; ++j)
                s[j] = (j < m) ? srtF[e + j] : s[0];
#pragma unroll
            for (int j = 0; j < 8; ++j)
                g[j] = *(const ushort2*)(Pf + (unsigned)s[j] * 128u + lo);
#pragma unroll
            for (int j = 0; j < 8; ++j) {
                if (j < m) {
                    ax += selu_f(bf2f(g[j].x) + qx);
                    ay += selu_f(bf2f(g[j].y) + qy);
                }
            }
        }
        ushort2 r; r.x = f2bf(ax); r.y = f2bf(ay);
        *(ushort2*)(aggF + (size_t)n * 128 + lo) = r;
    } else {
        const int n = (bid - NF / 4) * 4 + wid;
        const int b0 = baseC[n], b1 = baseC[n + 1];
        const float q = bf2f(R[(unsigned)n * 512u + 448 + lane]) + beC[lane];
        const unsigned clo = 384u + (unsigned)lane;
        float s = 0.0f;
        int e = b0;
        for (; e + 4 <= b1; e += 4) {
            const int s0 = srtC[e], s1 = srtC[e + 1];
            const int s2 = srtC[e + 2], s3 = srtC[e + 3];
            const ushort_t v0 = R[(unsigned)s0 * 512u + clo];
            const ushort_t v1 = R[(unsigned)s1 * 512u + clo];
            const ushort_t v2 = R[(unsigned)s2 * 512u + clo];
            const ushort_t v3 = R[(unsigned)s3 * 512u + clo];
            s += selu_f(bf2f(v0) + q);
            s += selu_f(bf2f(v1) + q);
            s += selu_f(bf2f(v2) + q);
            s += selu_f(bf2f(v3) + q);
        }
        for (; e < b1; ++e)
            s += selu_f(bf2f(R[(unsigned)srtC[e] * 512u + clo]) + q);
        aggC[(size_t)n * 64 + lane] = f2bf(s);
    }
}

// ---------------------------------------------------------------------------
// nodeSD: blocks 0..255: x_skip = selu(aggF@WnS_bot + UfS + bnS) -> outp f32
//         blocks 256..319: h1 = selu(concat(xb,agg1b)@Wn1 + bn1) in LDS,
//                          then RE = h1 @ WfE (fused gemmE) -> RE bf16
// ---------------------------------------------------------------------------
__global__ __launch_bounds__(256) void nodeSD_kernel(
    const ushort_t* __restrict__ aggF, const ushort_t* __restrict__ WfSn,
    const float* __restrict__ bnS, const ushort_t* __restrict__ UfS,
    float* __restrict__ outp,
    const ushort_t* __restrict__ xb, const ushort_t* __restrict__ agg1b,
    const ushort_t* __restrict__ Wf1n, const float* __restrict__ bn1,
    const ushort_t* __restrict__ WfE, ushort_t* __restrict__ RE) {
    __shared__ ushort_t h1s[64][72];
    const int tid = threadIdx.x;
    const int wid = tid >> 6, lane = tid & 63;
    const int klane = (lane >> 4) << 3;
    if (blockIdx.x < 256) {
        const int row_base = blockIdx.x * 64 + wid * 16;
        const int row_a = row_base + (lane & 15);
        short8v a[4];
#pragma unroll
        for (int f = 0; f < 4; ++f)
            a[f] = *(const short8v*)(aggF + (size_t)row_a * 128 + f * 32 + klane);
#pragma unroll
        for (int nt = 0; nt < 8; ++nt) {
            f32x4 acc = {0.0f, 0.0f, 0.0f, 0.0f};
#pragma unroll
            for (int f = 0; f < 4; ++f) {
                const short8v b =
                    *(const short8v*)(WfSn + (size_t)(nt * 4 + f) * 512 + lane * 8);
                acc = __builtin_amdgcn_mfma_f32_16x16x32_bf16(a[f], b, acc, 0, 0, 0);
            }
            const int col = nt * 16 + (lane & 15);
            const int r0 = row_base + ((lane >> 4) << 2);
#pragma unroll
            for (int r = 0; r < 4; ++r) {
                const size_t o = (size_t)(r0 + r) * 128 + col;
                outp[o] = selu_f(acc[r] + bnS[col] + bf2f(UfS[o]));
            }
        }
    } else {
        const int row_base = (blockIdx.x - 256) * 64 + wid * 16;
        const int row_a = row_base + (lane & 15);
        short8v a[6];
#pragma unroll
        for (int f = 0; f < 4; ++f)
            a[f] = *(const short8v*)(xb + (size_t)row_a * 128 + f * 32 + klane);
#pragma unroll
        for (int f = 0; f < 2; ++f)
            a[4 + f] = *(const short8v*)(agg1b + (size_t)row_a * 64 + f * 32 + klane);
#pragma unroll
        for (int nt = 0; nt < 4; ++nt) {
            f32x4 acc = {0.0f, 0.0f, 0.0f, 0.0f};
#pragma unroll
            for (int f = 0; f < 6; ++f) {
                const short8v b =
                    *(const short8v*)(Wf1n + (size_t)(nt * 6 + f) * 512 + lane * 8);
                acc = __builtin_amdgcn_mfma_f32_16x16x32_bf16(a[f], b, acc, 0, 0, 0);
            }
            const int col = nt * 16 + (lane & 15);
            const int lr0 = wid * 16 + ((lane >> 4) << 2);
#pragma unroll
            for (int r = 0; r < 4; ++r)
                h1s[lr0 + r][col] = f2bf(selu_f(acc[r] + bn1[col]));
        }
        __syncthreads();
        short8v ha[2];
#pragma unroll
        for (int f = 0; f < 2; ++f)
            ha[f] = *(const short8v*)&h1s[wid * 16 + (lane & 15)][f * 32 + klane];
#pragma unroll
        for (int nt = 0; nt < 24; ++nt) {
            f32x4 acc = {0.0f, 0.0f, 0.0f, 0.0f};
#pragma unroll
            for (int f = 0; f < 2; ++f) {
                const short8v b =
                    *(const short8v*)(WfE + (size_t)(nt * 2 + f) * 512 + lane * 8);
                acc = __builtin_amdgcn_mfma_f32_16x16x32_bf16(ha[f], b, acc, 0, 0, 0);
            }
            const int col = nt * 16 + (lane & 15);
            const int r0 = row_base + ((lane >> 4) << 2);
#pragma unroll
            for (int r = 0; r < 4; ++r)
                RE[(size_t)(r0 + r) * 384 + col] = f2bf(acc[r]);
        }
    }
}

// ---------------------------------------------------------------------------
// nodeH: v = selu(aggF@Wn2_bot + Uf2 + bn2) + x_skip; write outp; BN stats.
// ---------------------------------------------------------------------------
__global__ __launch_bounds__(256) void nodeH_kernel(
    const ushort_t* __restrict__ aggF, const ushort_t* __restrict__ Wf2n,
    const float* __restrict__ bn2, const ushort_t* __restrict__ Uf2,
    float* __restrict__ outp, float* __restrict__ stats) {
    __shared__ float s_sum[128], s_sq[128];
    const int tid = threadIdx.x;
    const int wid = tid >> 6, lane = tid & 63;
    const int klane = (lane >> 4) << 3;
    if (tid < 128) { s_sum[tid] = 0.0f; s_sq[tid] = 0.0f; }
    __syncthreads();
    const int row_base = blockIdx.x * 64 + wid * 16;
    const int row_a = row_base + (lane & 15);
    short8v a[4];
#pragma unroll
    for (int f = 0; f < 4; ++f)
        a[f] = *(const short8v*)(aggF + (size_t)row_a * 128 + f * 32 + klane);
#pragma unroll
    for (int nt = 0; nt < 8; ++nt) {
        f32x4 acc = {0.0f, 0.0f, 0.0f, 0.0f};
#pragma unroll
        for (int f = 0; f < 4; ++f) {
            const short8v b =
                *(const short8v*)(Wf2n + (size_t)(nt * 4 + f) * 512 + lane * 8);
            acc = __builtin_amdgcn_mfma_f32_16x16x32_bf16(a[f], b, acc, 0, 0, 0);
        }
        const int col = nt * 16 + (lane & 15);
        const int r0 = row_base + ((lane >> 4) << 2);
        float lsum = 0.0f, lsq = 0.0f;
#pragma unroll
        for (int r = 0; r < 4; ++r) {
            const size_t o = (size_t)(r0 + r) * 128 + col;
            float v = selu_f(acc[r] + bn2[col] + bf2f(Uf2[o])) + outp[o];
            outp[o] = v;
            lsum += v; lsq += v * v;
        }
        atomicAdd(&s_sum[nt * 16 + (lane & 15)], lsum);
        atomicAdd(&s_sq[nt * 16 + (lane & 15)], lsq);
    }
    __syncthreads();
    if (tid < 128) {
        atomicAdd(&stats[tid], s_sum[tid]);
        atomicAdd(&stats[128 + tid], s_sq[tid]);
    }
}

// ---------------------------------------------------------------------------
// BN normalize + SELU, in place on d_out.
// ---------------------------------------------------------------------------
__global__ __launch_bounds__(256) void bn_kernel(
    float* __restrict__ out, const float* __restrict__ stats,
    const float* __restrict__ gamma, const float* __restrict__ beta, int Nn) {
    const int i = blockIdx.x * blockDim.x + threadIdx.x;
    const int c = i & 127;
    const float invn = 1.0f / (float)Nn;
    float mu = stats[c] * invn;
    float var = stats[128 + c] * invn - mu * mu;
    float r = rsqrtf(var + 1e-5f);
    float v = (out[i] - mu) * r * gamma[c] + beta[c];
    out[i] = selu_f(v);
}

// ---------------------------------------------------------------------------
extern "C" void kernel_launch(void* const* d_in, const int* in_sizes, int n_in,
                              void* d_out, int out_size, void* d_ws, size_t ws_size,
                              hipStream_t stream) {
    const float* x     = (const float*)d_in[0];
    const float* pos_c = (const float*)d_in[1];
    const float* pos_f = (const float*)d_in[2];
    const int*   ei_c  = (const int*)d_in[3];
    const int*   ei_f  = (const int*)d_in[4];
    const float* We1 = (const float*)d_in[5];
    const float* be1 = (const float*)d_in[6];
    const float* Wn1 = (const float*)d_in[7];
    const float* bn1 = (const float*)d_in[8];
    const float* We2 = (const float*)d_in[9];
    const float* be2 = (const float*)d_in[10];
    const float* Wn2 = (const float*)d_in[11];
    const float* bn2 = (const float*)d_in[12];
    const float* WeS = (const float*)d_in[13];
    const float* beS = (const float*)d_in[14];
    const float* WnS = (const float*)d_in[15];
    const float* bnS = (const float*)d_in[16];
    const float* gamma = (const float*)d_in[17];
    const float* beta  = (const float*)d_in[18];

    char* w = (char*)d_ws;
    size_t o = 0;
    auto alloc = [&](size_t bytes) { void* p = w + o; o += (bytes + 255) & ~(size_t)255; return p; };
    float4*   meta    = (float4*)alloc((size_t)NF * 2 * sizeof(float4));
    ushort_t* RA      = (ushort_t*)alloc((size_t)NC * 512 * 2);   // also RE (aliased)
    ushort_t* Pf      = (ushort_t*)alloc((size_t)NF * 128 * 2);   // reused per phase
    ushort_t* Qf      = (ushort_t*)alloc((size_t)NF * 128 * 2);   // reused per phase
    ushort_t* Uf      = (ushort_t*)alloc((size_t)NF * 128 * 2);   // reused per phase
    ushort_t* aggF    = (ushort_t*)alloc((size_t)NF * 128 * 2);   // reused per phase
    ushort_t* agg1b   = (ushort_t*)alloc((size_t)NC * 64 * 2);
    ushort_t* xb      = (ushort_t*)alloc((size_t)NC * 128 * 2);
    ushort_t* WfA     = (ushort_t*)alloc(65536 * 2);
    ushort_t* WfE     = (ushort_t*)alloc(24576 * 2);
    ushort_t* WfSn    = (ushort_t*)alloc(16384 * 2);
    ushort_t* Wf1n    = (ushort_t*)alloc(12288 * 2);
    ushort_t* Wf2n    = (ushort_t*)alloc(16384 * 2);
    int*   cntF  = (int*)alloc((size_t)NF * sizeof(int));
    int*   baseF = (int*)alloc((size_t)(NF + 1) * sizeof(int));
    int*   cursF = (int*)alloc((size_t)NF * sizeof(int));
    int*   srtF  = (int*)alloc((size_t)EF * sizeof(int));
    int*   cntC  = (int*)alloc((size_t)NC * sizeof(int));
    int*   baseC = (int*)alloc((size_t)(NC + 1) * sizeof(int));
    int*   cursC = (int*)alloc((size_t)NC * sizeof(int));
    int*   srtC  = (int*)alloc((size_t)EC * sizeof(int));
    int*   cntG  = (int*)alloc((size_t)NCELL * sizeof(int));
    int*   baseG = (int*)alloc((size_t)(NCELL + 1) * sizeof(int));
    int*   cursG = (int*)alloc((size_t)NCELL * sizeof(int));
    float4* grecs = (float4*)alloc((size_t)NC * sizeof(float4));
    float* stats = (float*)alloc(256 * sizeof(float));
    ushort_t* RE = RA;               // RA dead once nodeSD starts
    float* outp = (float*)d_out;

    // 1. prep
    constexpr int PREP_TOTAL = NC * 128 + 65536 + 24576 + 16384 + 12288 + 16384
                             + NF + NC + NCELL + 256;
    prep_kernel<<<(PREP_TOTAL + 255) / 256, 256, 0, stream>>>(
        x, xb, WeS, WnS, We1, We2, Wn2, Wn1,
        WfA, WfE, WfSn, Wf1n, Wf2n, cntF, cntC, cntG, stats);

    // 2-4. merged counting sorts
    constexpr int SORT_ITEMS = EF + EC + NC;
    hist3_kernel<<<(SORT_ITEMS + 255) / 256, 256, 0, stream>>>(
        ei_f, ei_c, pos_c, cntF, cntC, cntG);
    scan3_kernel<<<3, 1024, 0, stream>>>(
        cntF, baseF, cursF, cntC, baseC, cursC, cntG, baseG, cursG);
    scatter3_kernel<<<(SORT_ITEMS + 255) / 256, 256, 0, stream>>>(
        ei_f, ei_c, pos_c, cursF, srtF, cursC, srtC, cursG, grecs);

    // 5. RA GEMM (bf16 out) + kNN
    gemmA_knn_kernel<<<768, 256, 0, stream>>>(
        xb, WfA, RA, pos_f, grecs, baseG, meta);

    // 6. pfS: materialize Pf/Qf/Uf from RA
    pf_kernel<512><<<NF * 64 / 256, 256, 0, stream>>>(RA, meta, beS, Pf, Qf, Uf);

    // 7. aggS: fine skip agg (1 gather/edge) + coarse agg1
    agg_kernel<true><<<NF / 4 + NC / 4, 256, 0, stream>>>(
        Pf, Qf, baseF, srtF, aggF, RA, baseC, srtC, be1, agg1b);

    // 8. nodeS (x_skip -> d_out) + node1 + fused gemmE (RE)
    nodeSD_kernel<<<320, 256, 0, stream>>>(
        aggF, WfSn, bnS, Uf, outp, xb, agg1b, Wf1n, bn1, WfE, RE);

    // 9. pf2: materialize Pf/Qf/Uf from RE
    pf_kernel<384><<<NF * 64 / 256, 256, 0, stream>>>(RE, meta, be2, Pf, Qf, Uf);

    // 10. aggH: fine mpl2 agg
    agg_kernel<false><<<NF / 4, 256, 0, stream>>>(
        Pf, Qf, baseF, srtF, aggF, nullptr, nullptr, nullptr, nullptr, nullptr);

    // 11. nodeH: final MLP + residual + BN stats
    nodeH_kernel<<<256, 256, 0, stream>>>(aggF, Wf2n, bn2, Uf, outp, stats);

    // 12. BN + SELU
    bn_kernel<<<NF * 128 / 256, 256, 0, stream>>>(outp, stats, gamma, beta, NF);
}

// Round 13
// 184.430 us; speedup vs baseline: 1.2777x; 1.0379x over previous
//
#include <hip/hip_runtime.h>

// ---------------------------------------------------------------------------
// Res_up block, round 13: single fine-edge pass. Coarse chain (agg1, node1,
// gemmE->RE) runs first; then pfBoth interpolates P/Q/U from RA AND RE in one
// kernel; aggBoth does ONE edge traversal computing both aggregations;
// nodeFinal runs both node GEMMs with x_skip in registers (d_out written
// once) + BN stats. 11 dispatches.
// Sizes fixed: Nc=4096, Nf=16384, Ec=65536, Ef=262144, Cin=128, Ch=64, Co=128.
// ---------------------------------------------------------------------------

#define SELU_SCALE 1.0507009873554805f
#define SELU_ALPHA 1.6732632423543772f

static constexpr int NC = 4096, NF = 16384, EC = 65536, EF = 262144;
static constexpr int G = 32, NCELL = G * G;

typedef __attribute__((ext_vector_type(8))) short short8v;
typedef __attribute__((ext_vector_type(4))) float f32x4;
typedef unsigned short ushort_t;
typedef unsigned long long u64;

__device__ __forceinline__ float selu_f(float x) {
    return x > 0.0f ? SELU_SCALE * x
                    : SELU_SCALE * SELU_ALPHA * (__expf(x) - 1.0f);
}
__device__ __forceinline__ ushort_t f2bf(float f) {
    unsigned u = __float_as_uint(f);
    u += 0x7FFFu + ((u >> 16) & 1u);
    return (ushort_t)(u >> 16);
}
__device__ __forceinline__ float bf2f(ushort_t u) {
    return __uint_as_float(((unsigned)u) << 16);
}
__device__ __forceinline__ int cell_of(float2 p) {
    int cx = (int)(p.x * (float)G); cx = cx > G - 1 ? G - 1 : cx;
    int cy = (int)(p.y * (float)G); cy = cy > G - 1 ? G - 1 : cy;
    return cy * G + cx;
}
__device__ __forceinline__ void ins3(u64& a0, u64& a1, u64& a2, u64 v) {
    if (v < a2) {
        if (v < a1) {
            a2 = a1;
            if (v < a0) { a1 = a0; a0 = v; } else a1 = v;
        } else a2 = v;
    }
}

// ---------------------------------------------------------------------------
// Fragment-major weight writer: Wf[(ntile*KC+kc)*512 + lane*8 + e] = W[k][col]
// ---------------------------------------------------------------------------
template <int K, typename F>
__device__ __forceinline__ void wfrag(F getw, ushort_t* __restrict__ dst, int idx) {
    constexpr int KC = K / 32;
    const int f = idx >> 9;
    const int r = idx & 511;
    const int lane = r >> 3;
    const int e = r & 7;
    const int ntile = f / KC;
    const int kc = f - ntile * KC;
    const int k = kc * 32 + ((lane >> 4) << 3) + e;
    const int col = ntile * 16 + (lane & 15);
    dst[idx] = f2bf(getw(k, col));
}

// ---------------------------------------------------------------------------
// prep: x->bf16, 5 weight-frag buffers, zero cnt/stats.
// ---------------------------------------------------------------------------
__global__ __launch_bounds__(256) void prep_kernel(
    const float* __restrict__ x, ushort_t* __restrict__ xb,
    const float* __restrict__ WeS, const float* __restrict__ WnS,
    const float* __restrict__ We1, const float* __restrict__ We2,
    const float* __restrict__ Wn2, const float* __restrict__ Wn1,
    ushort_t* __restrict__ WfA, ushort_t* __restrict__ WfE,
    ushort_t* __restrict__ WfSn, ushort_t* __restrict__ Wf1n,
    ushort_t* __restrict__ Wf2n,
    int* __restrict__ cntF, int* __restrict__ cntC, int* __restrict__ cntG,
    float* __restrict__ stats) {
    int i = blockIdx.x * 256 + threadIdx.x;
    if (i < NC * 128) { xb[i] = f2bf(x[i]); return; }
    i -= NC * 128;
    if (i < 65536) {   // RA weights: K=128, N=512
        wfrag<128>([&](int k, int j) {
            return j < 128 ? WeS[k * 128 + j]
                 : j < 256 ? WeS[(128 + k) * 128 + (j - 128)]
                 : j < 384 ? WnS[k * 128 + (j - 256)]
                 : j < 448 ? We1[k * 64 + (j - 384)]
                           : We1[(128 + k) * 64 + (j - 448)];
        }, WfA, i);
        return;
    }
    i -= 65536;
    if (i < 24576) {   // RE weights: K=64, N=384
        wfrag<64>([&](int k, int j) {
            return j < 128 ? We2[k * 128 + j]
                 : j < 256 ? We2[(64 + k) * 128 + (j - 128)]
                           : Wn2[k * 128 + (j - 256)];
        }, WfE, i);
        return;
    }
    i -= 24576;
    if (i < 16384) {   // nodeS: WnS bottom half, K=128, N=128
        wfrag<128>([&](int k, int j) { return WnS[(128 + k) * 128 + j]; }, WfSn, i);
        return;
    }
    i -= 16384;
    if (i < 12288) {   // node1: full Wn1, K=192, N=64
        wfrag<192>([&](int k, int j) { return Wn1[k * 64 + j]; }, Wf1n, i);
        return;
    }
    i -= 12288;
    if (i < 16384) {   // nodeH: Wn2 bottom, K=128, N=128
        wfrag<128>([&](int k, int j) { return Wn2[(64 + k) * 128 + j]; }, Wf2n, i);
        return;
    }
    i -= 16384;
    if (i < NF) { cntF[i] = 0; return; }
    i -= NF;
    if (i < NC) { cntC[i] = 0; return; }
    i -= NC;
    if (i < NCELL) { cntG[i] = 0; return; }
    i -= NCELL;
    if (i < 256) { stats[i] = 0.0f; return; }
}

// ---------------------------------------------------------------------------
// merged histogram / scan / scatter for {fine edges, coarse edges, grid cells}
// ---------------------------------------------------------------------------
__global__ __launch_bounds__(256) void hist3_kernel(
    const int* __restrict__ ei_f, const int* __restrict__ ei_c,
    const float* __restrict__ pos_c,
    int* __restrict__ cntF, int* __restrict__ cntC, int* __restrict__ cntG) {
    int i = blockIdx.x * 256 + threadIdx.x;
    if (i < EF) { atomicAdd(&cntF[ei_f[EF + i]], 1); return; }
    i -= EF;
    if (i < EC) { atomicAdd(&cntC[ei_c[EC + i]], 1); return; }
    i -= EC;
    if (i < NC) {
        float2 p = ((const float2*)pos_c)[i];
        atomicAdd(&cntG[cell_of(p)], 1);
    }
}

__global__ __launch_bounds__(1024) void scan3_kernel(
    int* __restrict__ cntF, int* __restrict__ baseF, int* __restrict__ cursF,
    int* __restrict__ cntC, int* __restrict__ baseC, int* __restrict__ cursC,
    int* __restrict__ cntG, int* __restrict__ baseG, int* __restrict__ cursG) {
    const int* cnt; int* base; int* curs; int n;
    if (blockIdx.x == 0)      { cnt = cntF; base = baseF; curs = cursF; n = NF; }
    else if (blockIdx.x == 1) { cnt = cntC; base = baseC; curs = cursC; n = NC; }
    else                      { cnt = cntG; base = baseG; curs = cursG; n = NCELL; }
    const int IT = n >> 10;
    __shared__ int part[1024];
    const int t = threadIdx.x;
    int loc[16];
    int s = 0;
#pragma unroll
    for (int i = 0; i < 16; ++i) {
        int v = (i < IT) ? cnt[t * IT + i] : 0;
        loc[i] = v; s += v;
    }
    part[t] = s;
    __syncthreads();
    for (int off = 1; off < 1024; off <<= 1) {
        int v = part[t];
        int u = (t >= off) ? part[t - off] : 0;
        __syncthreads();
        part[t] = v + u;
        __syncthreads();
    }
    int ex = (t == 0) ? 0 : part[t - 1];
#pragma unroll
    for (int i = 0; i < 16; ++i) {
        if (i < IT) {
            base[t * IT + i] = ex;
            curs[t * IT + i] = ex;
            ex += loc[i];
        }
    }
    if (t == 1023) base[n] = ex;
}

__global__ __launch_bounds__(256) void scatter3_kernel(
    const int* __restrict__ ei_f, const int* __restrict__ ei_c,
    const float* __restrict__ pos_c,
    int* __restrict__ cursF, int* __restrict__ srtF,
    int* __restrict__ cursC, int* __restrict__ srtC,
    int* __restrict__ cursG, float4* __restrict__ grecs) {
    int i = blockIdx.x * 256 + threadIdx.x;
    if (i < EF) {
        int pos = atomicAdd(&cursF[ei_f[EF + i]], 1);
        srtF[pos] = ei_f[i];
        return;
    }
    i -= EF;
    if (i < EC) {
        int pos = atomicAdd(&cursC[ei_c[EC + i]], 1);
        srtC[pos] = ei_c[i];
        return;
    }
    i -= EC;
    if (i < NC) {
        float2 p = ((const float2*)pos_c)[i];
        int pos = atomicAdd(&cursG[cell_of(p)], 1);
        float4 rec;
        rec.x = p.x; rec.y = p.y; rec.z = __int_as_float(i); rec.w = 0.0f;
        grecs[pos] = rec;
    }
}

// ---------------------------------------------------------------------------
// Fused: blocks 0..255 = RA GEMM (4096x512x128, bf16 out);
// blocks 256..767 = grid-kNN, 8 lanes per fine point.
// meta[2t] = idx bits (as float), meta[2t+1] = weights.
// ---------------------------------------------------------------------------
__global__ __launch_bounds__(256) void gemmA_knn_kernel(
    const ushort_t* __restrict__ xb, const ushort_t* __restrict__ WfA,
    ushort_t* __restrict__ RA,
    const float* __restrict__ pos_f, const float4* __restrict__ grecs,
    const int* __restrict__ baseG, float4* __restrict__ meta) {
    const int bid = blockIdx.x;
    const int tid = threadIdx.x;
    if (bid < 256) {
        const int wid = tid >> 6, lane = tid & 63;
        const int bx = bid >> 2, by = bid & 3;
        const int row_base = bx * 64 + wid * 16;
        const int row_a = row_base + (lane & 15);
        const int klane = (lane >> 4) << 3;
        short8v a[4];
#pragma unroll
        for (int f = 0; f < 4; ++f)
            a[f] = *(const short8v*)(xb + (size_t)row_a * 128 + f * 32 + klane);
#pragma unroll
        for (int nt = 0; nt < 8; ++nt) {
            const int ntg = by * 8 + nt;
            f32x4 acc = {0.0f, 0.0f, 0.0f, 0.0f};
#pragma unroll
            for (int f = 0; f < 4; ++f) {
                const short8v b =
                    *(const short8v*)(WfA + (size_t)(ntg * 4 + f) * 512 + lane * 8);
                acc = __builtin_amdgcn_mfma_f32_16x16x32_bf16(a[f], b, acc, 0, 0, 0);
            }
            const int col = ntg * 16 + (lane & 15);
            const int r0 = row_base + ((lane >> 4) << 2);
#pragma unroll
            for (int r = 0; r < 4; ++r)
                RA[(size_t)(r0 + r) * 512 + col] = f2bf(acc[r]);
        }
    } else {
        const int g8 = (bid - 256) * 256 + tid;    // 131072 = 8 * NF
        const int t = g8 >> 3;
        const int sub = g8 & 7;
        const float2 p = ((const float2*)pos_f)[t];
        int cx = (int)(p.x * (float)G); cx = cx > G - 1 ? G - 1 : cx;
        int cy = (int)(p.y * (float)G); cy = cy > G - 1 ? G - 1 : cy;
        const float h = 1.0f / (float)G;

        u64 b0 = ~0ull, b1 = ~0ull, b2 = ~0ull;

        {
            const int xx0 = cx - 1 < 0 ? 0 : cx - 1;
            const int xx1 = cx + 1 > G - 1 ? G - 1 : cx + 1;
            const int yy0 = cy - 1 < 0 ? 0 : cy - 1;
            const int yy1 = cy + 1 > G - 1 ? G - 1 : cy + 1;
            int rs[3], rl[3];
            int nr = 0;
            for (int yy = yy0; yy <= yy1; ++yy) {
                const int s = baseG[yy * G + xx0];
                const int e = baseG[yy * G + xx1 + 1];
                rs[nr] = s; rl[nr] = e - s; ++nr;
            }
            const int l0 = rl[0];
            const int l01 = l0 + (nr > 1 ? rl[1] : 0);
            const int m = l01 + (nr > 2 ? rl[2] : 0);
            for (int j = sub; j < m; j += 8) {
                int i;
                if (j < l0) i = rs[0] + j;
                else if (j < l01) i = rs[1] + (j - l0);
                else i = rs[2] + (j - l01);
                const float4 q = grecs[i];
                const float dx = p.x - q.x;
                const float dy = p.y - q.y;
                const float d = dx * dx + dy * dy;
                ins3(b0, b1, b2, ((u64)__float_as_uint(d) << 32) |
                                 (u64)__float_as_uint(q.z));
            }
#pragma unroll
            for (int mk = 1; mk <= 4; mk <<= 1) {
                const u64 e0 = __shfl_xor(b0, mk);
                const u64 e1 = __shfl_xor(b1, mk);
                const u64 e2 = __shfl_xor(b2, mk);
                ins3(b0, b1, b2, e0);
                ins3(b0, b1, b2, e1);
                ins3(b0, b1, b2, e2);
            }
        }

        for (int r = 2; r < G; ++r) {
            const float bd = __uint_as_float((unsigned)(b2 >> 32));
            const float lim = (float)(r - 1) * h;
            if (bd < lim * lim) break;
            u64 c0 = ~0ull, c1 = ~0ull, c2 = ~0ull;
            auto scan_cells = [&](int cell0, int cell1, int step) {
                for (int c = cell0; c <= cell1; c += step) {
                    const int s0 = baseG[c], s1 = baseG[c + 1];
                    for (int i = s0; i < s1; ++i) {
                        const float4 q = grecs[i];
                        const float dx = p.x - q.x;
                        const float dy = p.y - q.y;
                        const float d = dx * dx + dy * dy;
                        ins3(c0, c1, c2, ((u64)__float_as_uint(d) << 32) |
                                         (u64)__float_as_uint(q.z));
                    }
                }
            };
            const int side = sub & 3, phase = sub >> 2;
            const int x0 = cx - r < 0 ? 0 : cx - r;
            const int x1 = cx + r > G - 1 ? G - 1 : cx + r;
            const int yi0 = cy - r + 1 < 0 ? 0 : cy - r + 1;
            const int yi1 = cy + r - 1 > G - 1 ? G - 1 : cy + r - 1;
            if (side == 0) {
                if (cy - r >= 0) scan_cells((cy - r) * G + x0 + phase, (cy - r) * G + x1, 2);
            } else if (side == 1) {
                if (cy + r <= G - 1) scan_cells((cy + r) * G + x0 + phase, (cy + r) * G + x1, 2);
            } else if (side == 2) {
                if (cx - r >= 0 && yi0 + phase <= yi1)
                    scan_cells((yi0 + phase) * G + cx - r, yi1 * G + cx - r, 2 * G);
            } else {
                if (cx + r <= G - 1 && yi0 + phase <= yi1)
                    scan_cells((yi0 + phase) * G + cx + r, yi1 * G + cx + r, 2 * G);
            }
#pragma unroll
            for (int mk = 1; mk <= 4; mk <<= 1) {
                const u64 e0 = __shfl_xor(c0, mk);
                const u64 e1 = __shfl_xor(c1, mk);
                const u64 e2 = __shfl_xor(c2, mk);
                ins3(c0, c1, c2, e0);
                ins3(c0, c1, c2, e1);
                ins3(c0, c1, c2, e2);
            }
            ins3(b0, b1, b2, c0);
            ins3(b0, b1, b2, c1);
            ins3(b0, b1, b2, c2);
        }

        if (sub == 0) {
            const float d0 = __uint_as_float((unsigned)(b0 >> 32));
            const float d1 = __uint_as_float((unsigned)(b1 >> 32));
            const float d2 = __uint_as_float((unsigned)(b2 >> 32));
            const float w0 = 1.0f / fmaxf(d0, 1e-16f);
            const float w1 = 1.0f / fmaxf(d1, 1e-16f);
            const float w2 = 1.0f / fmaxf(d2, 1e-16f);
            const float s = 1.0f / (w0 + w1 + w2);
            float4 mi;
            mi.x = __uint_as_float((unsigned)(b0 & 0xffffffffu));
            mi.y = __uint_as_float((unsigned)(b1 & 0xffffffffu));
            mi.z = __uint_as_float((unsigned)(b2 & 0xffffffffu));
            mi.w = 0.0f;
            float4 mw;
            mw.x = w0 * s; mw.y = w1 * s; mw.z = w2 * s; mw.w = 0.0f;
            meta[2 * t] = mi;
            meta[2 * t + 1] = mw;
        }
    }
}

// ---------------------------------------------------------------------------
// agg1: coarse aggregation (RA cols 384=P1, 448=Q1), wave-per-node, unroll 4.
// ---------------------------------------------------------------------------
__global__ __launch_bounds__(256) void agg1_kernel(
    const ushort_t* __restrict__ R, const int* __restrict__ baseC,
    const int* __restrict__ srtC, const float* __restrict__ beC,
    ushort_t* __restrict__ aggC) {
    const int n = blockIdx.x * 4 + (threadIdx.x >> 6);
    const int lane = threadIdx.x & 63;
    const int b0 = baseC[n], b1 = baseC[n + 1];
    const float q = bf2f(R[(unsigned)n * 512u + 448 + lane]) + beC[lane];
    const unsigned clo = 384u + (unsigned)lane;
    float s = 0.0f;
    int e = b0;
    for (; e + 4 <= b1; e += 4) {
        const int s0 = srtC[e], s1 = srtC[e + 1];
        const int s2 = srtC[e + 2], s3 = srtC[e + 3];
        const ushort_t v0 = R[(unsigned)s0 * 512u + clo];
        const ushort_t v1 = R[(unsigned)s1 * 512u + clo];
        const ushort_t v2 = R[(unsigned)s2 * 512u + clo];
        const ushort_t v3 = R[(unsigned)s3 * 512u + clo];
        s += selu_f(bf2f(v0) + q);
        s += selu_f(bf2f(v1) + q);
        s += selu_f(bf2f(v2) + q);
        s += selu_f(bf2f(v3) + q);
    }
    for (; e < b1; ++e)
        s += selu_f(bf2f(R[(unsigned)srtC[e] * 512u + clo]) + q);
    aggC[(size_t)n * 64 + lane] = f2bf(s);
}

// ---------------------------------------------------------------------------
// nodeD: h1 = selu(concat(xb,agg1b)@Wn1 + bn1) in LDS, then RE = h1 @ WfE.
// Grid: 64 blocks (4096 rows / 64).
// ---------------------------------------------------------------------------
__global__ __launch_bounds__(256) void nodeD_kernel(
    const ushort_t* __restrict__ xb, const ushort_t* __restrict__ agg1b,
    const ushort_t* __restrict__ Wf1n, const float* __restrict__ bn1,
    const ushort_t* __restrict__ WfE, ushort_t* __restrict__ RE) {
    __shared__ ushort_t h1s[64][72];
    const int tid = threadIdx.x;
    const int wid = tid >> 6, lane = tid & 63;
    const int klane = (lane >> 4) << 3;
    const int row_base = blockIdx.x * 64 + wid * 16;
    const int row_a = row_base + (lane & 15);
    short8v a[6];
#pragma unroll
    for (int f = 0; f < 4; ++f)
        a[f] = *(const short8v*)(xb + (size_t)row_a * 128 + f * 32 + klane);
#pragma unroll
    for (int f = 0; f < 2; ++f)
        a[4 + f] = *(const short8v*)(agg1b + (size_t)row_a * 64 + f * 32 + klane);
#pragma unroll
    for (int nt = 0; nt < 4; ++nt) {
        f32x4 acc = {0.0f, 0.0f, 0.0f, 0.0f};
#pragma unroll
        for (int f = 0; f < 6; ++f) {
            const short8v b =
                *(const short8v*)(Wf1n + (size_t)(nt * 6 + f) * 512 + lane * 8);
            acc = __builtin_amdgcn_mfma_f32_16x16x32_bf16(a[f], b, acc, 0, 0, 0);
        }
        const int col = nt * 16 + (lane & 15);
        const int lr0 = wid * 16 + ((lane >> 4) << 2);
#pragma unroll
        for (int r = 0; r < 4; ++r)
            h1s[lr0 + r][col] = f2bf(selu_f(acc[r] + bn1[col]));
    }
    __syncthreads();
    short8v ha[2];
#pragma unroll
    for (int f = 0; f < 2; ++f)
        ha[f] = *(const short8v*)&h1s[wid * 16 + (lane & 15)][f * 32 + klane];
#pragma unroll
    for (int nt = 0; nt < 24; ++nt) {
        f32x4 acc = {0.0f, 0.0f, 0.0f, 0.0f};
#pragma unroll
        for (int f = 0; f < 2; ++f) {
            const short8v b =
                *(const short8v*)(WfE + (size_t)(nt * 2 + f) * 512 + lane * 8);
            acc = __builtin_amdgcn_mfma_f32_16x16x32_bf16(ha[f], b, acc, 0, 0, 0);
        }
        const int col = nt * 16 + (lane & 15);
        const int r0 = row_base + ((lane >> 4) << 2);
#pragma unroll
        for (int r = 0; r < 4; ++r)
            RE[(size_t)(r0 + r) * 384 + col] = f2bf(acc[r]);
    }
}

// ---------------------------------------------------------------------------
// pfBoth: per fine node, interpolate P/Q/U from RA (stride 512) AND RE
// (stride 384). 18 independent ushort2 gathers per lane. Wave-per-node.
// ---------------------------------------------------------------------------
__global__ __launch_bounds__(256) void pfboth_kernel(
    const ushort_t* __restrict__ RA, const ushort_t* __restrict__ RE,
    const float4* __restrict__ meta,
    const float* __restrict__ beS, const float* __restrict__ be2,
    ushort_t* __restrict__ PfS, ushort_t* __restrict__ QfS,
    ushort_t* __restrict__ UfS,
    ushort_t* __restrict__ Pf2, ushort_t* __restrict__ Qf2,
    ushort_t* __restrict__ Uf2) {
    const int gid = blockIdx.x * 256 + threadIdx.x;
    const int n = gid >> 6, lane = gid & 63;
    const float4 mi = meta[2 * n];
    const float4 mw = meta[2 * n + 1];
    const unsigned lo = (unsigned)(lane * 2);
    const unsigned i0 = __float_as_uint(mi.x);
    const unsigned i1 = __float_as_uint(mi.y);
    const unsigned i2 = __float_as_uint(mi.z);
    const unsigned a0 = i0 * 512 + lo, a1 = i1 * 512 + lo, a2 = i2 * 512 + lo;
    const unsigned e0 = i0 * 384 + lo, e1 = i1 * 384 + lo, e2 = i2 * 384 + lo;
    // RA gathers
    const ushort2 pA0 = *(const ushort2*)(RA + a0);
    const ushort2 pA1 = *(const ushort2*)(RA + a1);
    const ushort2 pA2 = *(const ushort2*)(RA + a2);
    const ushort2 qA0 = *(const ushort2*)(RA + a0 + 128);
    const ushort2 qA1 = *(const ushort2*)(RA + a1 + 128);
    const ushort2 qA2 = *(const ushort2*)(RA + a2 + 128);
    const ushort2 uA0 = *(const ushort2*)(RA + a0 + 256);
    const ushort2 uA1 = *(const ushort2*)(RA + a1 + 256);
    const ushort2 uA2 = *(const ushort2*)(RA + a2 + 256);
    // RE gathers
    const ushort2 pE0 = *(const ushort2*)(RE + e0);
    const ushort2 pE1 = *(const ushort2*)(RE + e1);
    const ushort2 pE2 = *(const ushort2*)(RE + e2);
    const ushort2 qE0 = *(const ushort2*)(RE + e0 + 128);
    const ushort2 qE1 = *(const ushort2*)(RE + e1 + 128);
    const ushort2 qE2 = *(const ushort2*)(RE + e2 + 128);
    const ushort2 uE0 = *(const ushort2*)(RE + e0 + 256);
    const ushort2 uE1 = *(const ushort2*)(RE + e1 + 256);
    const ushort2 uE2 = *(const ushort2*)(RE + e2 + 256);
    const float2 bS = *(const float2*)(beS + lane * 2);
    const float2 b2 = *(const float2*)(be2 + lane * 2);
    ushort2 o;
    o.x = f2bf(mw.x * bf2f(pA0.x) + mw.y * bf2f(pA1.x) + mw.z * bf2f(pA2.x));
    o.y = f2bf(mw.x * bf2f(pA0.y) + mw.y * bf2f(pA1.y) + mw.z * bf2f(pA2.y));
    *(ushort2*)(PfS + (size_t)n * 128 + lo) = o;
    o.x = f2bf(mw.x * bf2f(qA0.x) + mw.y * bf2f(qA1.x) + mw.z * bf2f(qA2.x) + bS.x);
    o.y = f2bf(mw.x * bf2f(qA0.y) + mw.y * bf2f(qA1.y) + mw.z * bf2f(qA2.y) + bS.y);
    *(ushort2*)(QfS + (size_t)n * 128 + lo) = o;
    o.x = f2bf(mw.x * bf2f(uA0.x) + mw.y * bf2f(uA1.x) + mw.z * bf2f(uA2.x));
    o.y = f2bf(mw.x * bf2f(uA0.y) + mw.y * bf2f(uA1.y) + mw.z * bf2f(uA2.y));
    *(ushort2*)(UfS + (size_t)n * 128 + lo) = o;
    o.x = f2bf(mw.x * bf2f(pE0.x) + mw.y * bf2f(pE1.x) + mw.z * bf2f(pE2.x));
    o.y = f2bf(mw.x * bf2f(pE0.y) + mw.y * bf2f(pE1.y) + mw.z * bf2f(pE2.y));
    *(ushort2*)(Pf2 + (size_t)n * 128 + lo) = o;
    o.x = f2bf(mw.x * bf2f(qE0.x) + mw.y * bf2f(qE1.x) + mw.z * bf2f(qE2.x) + b2.x);
    o.y = f2bf(mw.x * bf2f(qE0.y) + mw.y * bf2f(qE1.y) + mw.z * bf2f(qE2.y) + b2.y);
    *(ushort2*)(Qf2 + (size_t)n * 128 + lo) = o;
    o.x = f2bf(mw.x * bf2f(uE0.x) + mw.y * bf2f(uE1.x) + mw.z * bf2f(uE2.x));
    o.y = f2bf(mw.x * bf2f(uE0.y) + mw.y * bf2f(uE1.y) + mw.z * bf2f(uE2.y));
    *(ushort2*)(Uf2 + (size_t)n * 128 + lo) = o;
}

// ---------------------------------------------------------------------------
// aggBoth: ONE edge traversal computing both aggregations.
// Per edge: 1 uniform srt load + 2 gathers (PfS, Pf2). Unroll 8.
// ---------------------------------------------------------------------------
__global__ __launch_bounds__(256) void aggboth_kernel(
    const ushort_t* __restrict__ PfS, const ushort_t* __restrict__ QfS,
    const ushort_t* __restrict__ Pf2, const ushort_t* __restrict__ Qf2,
    const int* __restrict__ baseF, const int* __restrict__ srtF,
    ushort_t* __restrict__ aggS, ushort_t* __restrict__ agg2) {
    const int n = blockIdx.x * 4 + (threadIdx.x >> 6);
    const int lane = threadIdx.x & 63;
    const unsigned lo = (unsigned)(lane * 2);
    const ushort2 qSv = *(const ushort2*)(QfS + (size_t)n * 128 + lo);
    const ushort2 q2v = *(const ushort2*)(Qf2 + (size_t)n * 128 + lo);
    const float qSx = bf2f(qSv.x), qSy = bf2f(qSv.y);
    const float q2x = bf2f(q2v.x), q2y = bf2f(q2v.y);
    const int b0 = baseF[n], b1 = baseF[n + 1];
    float aSx = 0.0f, aSy = 0.0f, a2x = 0.0f, a2y = 0.0f;
    int e = b0;
    for (; e + 8 <= b1; e += 8) {
        int s[8];
#pragma unroll
        for (int j = 0; j < 8; ++j) s[j] = srtF[e + j];
        ushort2 gS[8], g2[8];
#pragma unroll
        for (int j = 0; j < 8; ++j) {
            gS[j] = *(const ushort2*)(PfS + (unsigned)s[j] * 128u + lo);
            g2[j] = *(const ushort2*)(Pf2 + (unsigned)s[j] * 128u + lo);
        }
#pragma unroll
        for (int j = 0; j < 8; ++j) {
            aSx += selu_f(bf2f(gS[j].x) + qSx);
            aSy += selu_f(bf2f(gS[j].y) + qSy);
            a2x += selu_f(bf2f(g2[j].x) + q2x);
            a2y += selu_f(bf2f(g2[j].y) + q2y);
        }
    }
    if (e < b1) {
        int s[8];
        ushort2 gS[8], g2[8];
        const int m = b1 - e;
#pragma unroll
        for (int j = 0; j < 8; ++j)
            s[j] = (j < m) ? srtF[e + j] : s[0];
#pragma unroll
        for (int j = 0; j < 8; ++j) {
            gS[j] = *(const ushort2*)(PfS + (unsigned)s[j] * 128u + lo);
            g2[j] = *(const ushort2*)(Pf2 + (unsigned)s[j] * 128u + lo);
        }
#pragma unroll
        for (int j = 0; j < 8; ++j) {
            if (j < m) {
                aSx += selu_f(bf2f(gS[j].x) + qSx);
                aSy += selu_f(bf2f(gS[j].y) + qSy);
                a2x += selu_f(bf2f(g2[j].x) + q2x);
                a2y += selu_f(bf2f(g2[j].y) + q2y);
            }
        }
    }
    ushort2 r;
    r.x = f2bf(aSx); r.y = f2bf(aSy);
    *(ushort2*)(aggS + (size_t)n * 128 + lo) = r;
    r.x = f2bf(a2x); r.y = f2bf(a2y);
    *(ushort2*)(agg2 + (size_t)n * 128 + lo) = r;
}

// ---------------------------------------------------------------------------
// nodeFinal: x_skip = selu(aggS@WfSn + UfS + bnS)  (registers only)
//            h      = selu(agg2@Wf2n + Uf2 + bn2)
//            v = h + x_skip -> outp; BN stats accumulated.
// ---------------------------------------------------------------------------
__global__ __launch_bounds__(256) void nodeF_kernel(
    const ushort_t* __restrict__ aggS, const ushort_t* __restrict__ WfSn,
    const float* __restrict__ bnS, const ushort_t* __restrict__ UfS,
    const ushort_t* __restrict__ agg2, const ushort_t* __restrict__ Wf2n,
    const float* __restrict__ bn2, const ushort_t* __restrict__ Uf2,
    float* __restrict__ outp, float* __restrict__ stats) {
    __shared__ float s_sum[128], s_sq[128];
    const int tid = threadIdx.x;
    const int wid = tid >> 6, lane = tid & 63;
    const int klane = (lane >> 4) << 3;
    if (tid < 128) { s_sum[tid] = 0.0f; s_sq[tid] = 0.0f; }
    __syncthreads();
    const int row_base = blockIdx.x * 64 + wid * 16;
    const int row_a = row_base + (lane & 15);
    short8v aS[4], a2[4];
#pragma unroll
    for (int f = 0; f < 4; ++f) {
        aS[f] = *(const short8v*)(aggS + (size_t)row_a * 128 + f * 32 + klane);
        a2[f] = *(const short8v*)(agg2 + (size_t)row_a * 128 + f * 32 + klane);
    }
#pragma unroll
    for (int nt = 0; nt < 8; ++nt) {
        f32x4 accS = {0.0f, 0.0f, 0.0f, 0.0f};
        f32x4 acc2 = {0.0f, 0.0f, 0.0f, 0.0f};
#pragma unroll
        for (int f = 0; f < 4; ++f) {
            const short8v bS =
                *(const short8v*)(WfSn + (size_t)(nt * 4 + f) * 512 + lane * 8);
            const short8v b2 =
                *(const short8v*)(Wf2n + (size_t)(nt * 4 + f) * 512 + lane * 8);
            accS = __builtin_amdgcn_mfma_f32_16x16x32_bf16(aS[f], bS, accS, 0, 0, 0);
            acc2 = __builtin_amdgcn_mfma_f32_16x16x32_bf16(a2[f], b2, acc2, 0, 0, 0);
        }
        const int col = nt * 16 + (lane & 15);
        const int r0 = row_base + ((lane >> 4) << 2);
        float lsum = 0.0f, lsq = 0.0f;
#pragma unroll
        for (int r = 0; r < 4; ++r) {
            const size_t o = (size_t)(r0 + r) * 128 + col;
            const float xs = selu_f(accS[r] + bnS[col] + bf2f(UfS[o]));
            const float hh = selu_f(acc2[r] + bn2[col] + bf2f(Uf2[o]));
            const float v = hh + xs;
            outp[o] = v;
            lsum += v; lsq += v * v;
        }
        atomicAdd(&s_sum[nt * 16 + (lane & 15)], lsum);
        atomicAdd(&s_sq[nt * 16 + (lane & 15)], lsq);
    }
    __syncthreads();
    if (tid < 128) {
        atomicAdd(&stats[tid], s_sum[tid]);
        atomicAdd(&stats[128 + tid], s_sq[tid]);
    }
}

// ---------------------------------------------------------------------------
// BN normalize + SELU, in place on d_out.
// ---------------------------------------------------------------------------
__global__ __launch_bounds__(256) void bn_kernel(
    float* __restrict__ out, const float* __restrict__ stats,
    const float* __restrict__ gamma, const float* __restrict__ beta, int Nn) {
    const int i = blockIdx.x * blockDim.x + threadIdx.x;
    const int c = i & 127;
    const float invn = 1.0f / (float)Nn;
    float mu = stats[c] * invn;
    float var = stats[128 + c] * invn - mu * mu;
    float r = rsqrtf(var + 1e-5f);
    float v = (out[i] - mu) * r * gamma[c] + beta[c];
    out[i] = selu_f(v);
}

// ---------------------------------------------------------------------------
extern "C" void kernel_launch(void* const* d_in, const int* in_sizes, int n_in,
                              void* d_out, int out_size, void* d_ws, size_t ws_size,
                              hipStream_t stream) {
    const float* x     = (const float*)d_in[0];
    const float* pos_c = (const float*)d_in[1];
    const float* pos_f = (const float*)d_in[2];
    const int*   ei_c  = (const int*)d_in[3];
    const int*   ei_f  = (const int*)d_in[4];
    const float* We1 = (const float*)d_in[5];
    const float* be1 = (const float*)d_in[6];
    const float* Wn1 = (const float*)d_in[7];
    const float* bn1 = (const float*)d_in[8];
    const float* We2 = (const float*)d_in[9];
    const float* be2 = (const float*)d_in[10];
    const float* Wn2 = (const float*)d_in[11];
    const float* bn2 = (const float*)d_in[12];
    const float* WeS = (const float*)d_in[13];
    const float* beS = (const float*)d_in[14];
    const float* WnS = (const float*)d_in[15];
    const float* bnS = (const float*)d_in[16];
    const float* gamma = (const float*)d_in[17];
    const float* beta  = (const float*)d_in[18];

    char* w = (char*)d_ws;
    size_t o = 0;
    auto alloc = [&](size_t bytes) { void* p = w + o; o += (bytes + 255) & ~(size_t)255; return p; };
    float4*   meta    = (float4*)alloc((size_t)NF * 2 * sizeof(float4));
    ushort_t* RA      = (ushort_t*)alloc((size_t)NC * 512 * 2);
    ushort_t* RE      = (ushort_t*)alloc((size_t)NC * 384 * 2);
    ushort_t* PfS     = (ushort_t*)alloc((size_t)NF * 128 * 2);
    ushort_t* QfS     = (ushort_t*)alloc((size_t)NF * 128 * 2);
    ushort_t* UfS     = (ushort_t*)alloc((size_t)NF * 128 * 2);
    ushort_t* Pf2     = (ushort_t*)alloc((size_t)NF * 128 * 2);
    ushort_t* Qf2     = (ushort_t*)alloc((size_t)NF * 128 * 2);
    ushort_t* Uf2     = (ushort_t*)alloc((size_t)NF * 128 * 2);
    ushort_t* aggS    = (ushort_t*)alloc((size_t)NF * 128 * 2);
    ushort_t* agg2    = (ushort_t*)alloc((size_t)NF * 128 * 2);
    ushort_t* agg1b   = (ushort_t*)alloc((size_t)NC * 64 * 2);
    ushort_t* xb      = (ushort_t*)alloc((size_t)NC * 128 * 2);
    ushort_t* WfA     = (ushort_t*)alloc(65536 * 2);
    ushort_t* WfE     = (ushort_t*)alloc(24576 * 2);
    ushort_t* WfSn    = (ushort_t*)alloc(16384 * 2);
    ushort_t* Wf1n    = (ushort_t*)alloc(12288 * 2);
    ushort_t* Wf2n    = (ushort_t*)alloc(16384 * 2);
    int*   cntF  = (int*)alloc((size_t)NF * sizeof(int));
    int*   baseF = (int*)alloc((size_t)(NF + 1) * sizeof(int));
    int*   cursF = (int*)alloc((size_t)NF * sizeof(int));
    int*   srtF  = (int*)alloc((size_t)EF * sizeof(int));
    int*   cntC  = (int*)alloc((size_t)NC * sizeof(int));
    int*   baseC = (int*)alloc((size_t)(NC + 1) * sizeof(int));
    int*   cursC = (int*)alloc((size_t)NC * sizeof(int));
    int*   srtC  = (int*)alloc((size_t)EC * sizeof(int));
    int*   cntG  = (int*)alloc((size_t)NCELL * sizeof(int));
    int*   baseG = (int*)alloc((size_t)(NCELL + 1) * sizeof(int));
    int*   cursG = (int*)alloc((size_t)NCELL * sizeof(int));
    float4* grecs = (float4*)alloc((size_t)NC * sizeof(float4));
    float* stats = (float*)alloc(256 * sizeof(float));
    float* outp = (float*)d_out;

    // 1. prep
    constexpr int PREP_TOTAL = NC * 128 + 65536 + 24576 + 16384 + 12288 + 16384
                             + NF + NC + NCELL + 256;
    prep_kernel<<<(PREP_TOTAL + 255) / 256, 256, 0, stream>>>(
        x, xb, WeS, WnS, We1, We2, Wn2, Wn1,
        WfA, WfE, WfSn, Wf1n, Wf2n, cntF, cntC, cntG, stats);

    // 2-4. merged counting sorts
    constexpr int SORT_ITEMS = EF + EC + NC;
    hist3_kernel<<<(SORT_ITEMS + 255) / 256, 256, 0, stream>>>(
        ei_f, ei_c, pos_c, cntF, cntC, cntG);
    scan3_kernel<<<3, 1024, 0, stream>>>(
        cntF, baseF, cursF, cntC, baseC, cursC, cntG, baseG, cursG);
    scatter3_kernel<<<(SORT_ITEMS + 255) / 256, 256, 0, stream>>>(
        ei_f, ei_c, pos_c, cursF, srtF, cursC, srtC, cursG, grecs);

    // 5. RA GEMM (bf16 out) + kNN
    gemmA_knn_kernel<<<768, 256, 0, stream>>>(
        xb, WfA, RA, pos_f, grecs, baseG, meta);

    // 6. coarse aggregation (mpl1)
    agg1_kernel<<<NC / 4, 256, 0, stream>>>(RA, baseC, srtC, be1, agg1b);

    // 7. node1 + gemmE -> RE
    nodeD_kernel<<<NC / 64, 256, 0, stream>>>(xb, agg1b, Wf1n, bn1, WfE, RE);

    // 8. pfBoth: interpolate P/Q/U from RA and RE
    pfboth_kernel<<<NF / 4, 256, 0, stream>>>(
        RA, RE, meta, beS, be2, PfS, QfS, UfS, Pf2, Qf2, Uf2);

    // 9. aggBoth: single edge traversal, both aggregations
    aggboth_kernel<<<NF / 4, 256, 0, stream>>>(
        PfS, QfS, Pf2, Qf2, baseF, srtF, aggS, agg2);

    // 10. nodeFinal: both node GEMMs + residual + BN stats
    nodeF_kernel<<<NF / 64, 256, 0, stream>>>(
        aggS, WfSn, bnS, UfS, agg2, Wf2n, bn2, Uf2, outp, stats);

    // 11. BN + SELU
    bn_kernel<<<NF * 128 / 256, 256, 0, stream>>>(outp, stats, gamma, beta, NF);
}

// Round 14
// 144.393 us; speedup vs baseline: 1.6320x; 1.2773x over previous
//
#include <hip/hip_runtime.h>

// ---------------------------------------------------------------------------
// Res_up block, round 14: round 13 +
//  - direct-scatter fixed-stride buckets (no hist/scan; caps 64/64/32)
//  - PfS/Pf2 and QfS/Qf2 interleaved (PF/QF ushort4) -> aggBoth is ONE
//    8B gather per edge
// 9 dispatches.
// Sizes fixed: Nc=4096, Nf=16384, Ec=65536, Ef=262144, Cin=128, Ch=64, Co=128.
// ---------------------------------------------------------------------------

#define SELU_SCALE 1.0507009873554805f
#define SELU_ALPHA 1.6732632423543772f

static constexpr int NC = 4096, NF = 16384, EC = 65536, EF = 262144;
static constexpr int G = 32, NCELL = G * G;
static constexpr int CAPF = 64, CAPC = 64, CAPG = 32;

typedef __attribute__((ext_vector_type(8))) short short8v;
typedef __attribute__((ext_vector_type(4))) float f32x4;
typedef unsigned short ushort_t;
typedef unsigned long long u64;

__device__ __forceinline__ float selu_f(float x) {
    return x > 0.0f ? SELU_SCALE * x
                    : SELU_SCALE * SELU_ALPHA * (__expf(x) - 1.0f);
}
__device__ __forceinline__ ushort_t f2bf(float f) {
    unsigned u = __float_as_uint(f);
    u += 0x7FFFu + ((u >> 16) & 1u);
    return (ushort_t)(u >> 16);
}
__device__ __forceinline__ float bf2f(ushort_t u) {
    return __uint_as_float(((unsigned)u) << 16);
}
__device__ __forceinline__ int cell_of(float2 p) {
    int cx = (int)(p.x * (float)G); cx = cx > G - 1 ? G - 1 : cx;
    int cy = (int)(p.y * (float)G); cy = cy > G - 1 ? G - 1 : cy;
    return cy * G + cx;
}
__device__ __forceinline__ void ins3(u64& a0, u64& a1, u64& a2, u64 v) {
    if (v < a2) {
        if (v < a1) {
            a2 = a1;
            if (v < a0) { a1 = a0; a0 = v; } else a1 = v;
        } else a2 = v;
    }
}

// ---------------------------------------------------------------------------
// Fragment-major weight writer: Wf[(ntile*KC+kc)*512 + lane*8 + e] = W[k][col]
// ---------------------------------------------------------------------------
template <int K, typename F>
__device__ __forceinline__ void wfrag(F getw, ushort_t* __restrict__ dst, int idx) {
    constexpr int KC = K / 32;
    const int f = idx >> 9;
    const int r = idx & 511;
    const int lane = r >> 3;
    const int e = r & 7;
    const int ntile = f / KC;
    const int kc = f - ntile * KC;
    const int k = kc * 32 + ((lane >> 4) << 3) + e;
    const int col = ntile * 16 + (lane & 15);
    dst[idx] = f2bf(getw(k, col));
}

// ---------------------------------------------------------------------------
// prep: x->bf16, 5 weight-frag buffers, zero cnt/stats.
// ---------------------------------------------------------------------------
__global__ __launch_bounds__(256) void prep_kernel(
    const float* __restrict__ x, ushort_t* __restrict__ xb,
    const float* __restrict__ WeS, const float* __restrict__ WnS,
    const float* __restrict__ We1, const float* __restrict__ We2,
    const float* __restrict__ Wn2, const float* __restrict__ Wn1,
    ushort_t* __restrict__ WfA, ushort_t* __restrict__ WfE,
    ushort_t* __restrict__ WfSn, ushort_t* __restrict__ Wf1n,
    ushort_t* __restrict__ Wf2n,
    int* __restrict__ cntF, int* __restrict__ cntC, int* __restrict__ cntG,
    float* __restrict__ stats) {
    int i = blockIdx.x * 256 + threadIdx.x;
    if (i < NC * 128) { xb[i] = f2bf(x[i]); return; }
    i -= NC * 128;
    if (i < 65536) {   // RA weights: K=128, N=512
        wfrag<128>([&](int k, int j) {
            return j < 128 ? WeS[k * 128 + j]
                 : j < 256 ? WeS[(128 + k) * 128 + (j - 128)]
                 : j < 384 ? WnS[k * 128 + (j - 256)]
                 : j < 448 ? We1[k * 64 + (j - 384)]
                           : We1[(128 + k) * 64 + (j - 448)];
        }, WfA, i);
        return;
    }
    i -= 65536;
    if (i < 24576) {   // RE weights: K=64, N=384
        wfrag<64>([&](int k, int j) {
            return j < 128 ? We2[k * 128 + j]
                 : j < 256 ? We2[(64 + k) * 128 + (j - 128)]
                           : Wn2[k * 128 + (j - 256)];
        }, WfE, i);
        return;
    }
    i -= 24576;
    if (i < 16384) {   // nodeS: WnS bottom half, K=128, N=128
        wfrag<128>([&](int k, int j) { return WnS[(128 + k) * 128 + j]; }, WfSn, i);
        return;
    }
    i -= 16384;
    if (i < 12288) {   // node1: full Wn1, K=192, N=64
        wfrag<192>([&](int k, int j) { return Wn1[k * 64 + j]; }, Wf1n, i);
        return;
    }
    i -= 12288;
    if (i < 16384) {   // nodeH: Wn2 bottom, K=128, N=128
        wfrag<128>([&](int k, int j) { return Wn2[(64 + k) * 128 + j]; }, Wf2n, i);
        return;
    }
    i -= 16384;
    if (i < NF) { cntF[i] = 0; return; }
    i -= NF;
    if (i < NC) { cntC[i] = 0; return; }
    i -= NC;
    if (i < NCELL) { cntG[i] = 0; return; }
    i -= NCELL;
    if (i < 256) { stats[i] = 0.0f; return; }
}

// ---------------------------------------------------------------------------
// Direct scatter into fixed-stride buckets (counts double as cursors).
// ---------------------------------------------------------------------------
__global__ __launch_bounds__(256) void scatter_kernel(
    const int* __restrict__ ei_f, const int* __restrict__ ei_c,
    const float* __restrict__ pos_c,
    int* __restrict__ cntF, int* __restrict__ srtF,
    int* __restrict__ cntC, int* __restrict__ srtC,
    int* __restrict__ cntG, float4* __restrict__ grecs) {
    int i = blockIdx.x * 256 + threadIdx.x;
    if (i < EF) {
        const int dst = ei_f[EF + i];
        const int slot = atomicAdd(&cntF[dst], 1);
        srtF[dst * CAPF + slot] = ei_f[i];
        return;
    }
    i -= EF;
    if (i < EC) {
        const int dst = ei_c[EC + i];
        const int slot = atomicAdd(&cntC[dst], 1);
        srtC[dst * CAPC + slot] = ei_c[i];
        return;
    }
    i -= EC;
    if (i < NC) {
        const float2 p = ((const float2*)pos_c)[i];
        const int c = cell_of(p);
        const int slot = atomicAdd(&cntG[c], 1);
        float4 rec;
        rec.x = p.x; rec.y = p.y; rec.z = __int_as_float(i); rec.w = 0.0f;
        grecs[c * CAPG + slot] = rec;
    }
}

// ---------------------------------------------------------------------------
// Fused: blocks 0..255 = RA GEMM (4096x512x128, bf16 out);
// blocks 256..767 = grid-kNN, 8 lanes per fine point (bucketed cells).
// meta[2t] = idx bits (as float), meta[2t+1] = weights.
// ---------------------------------------------------------------------------
__global__ __launch_bounds__(256) void gemmA_knn_kernel(
    const ushort_t* __restrict__ xb, const ushort_t* __restrict__ WfA,
    ushort_t* __restrict__ RA,
    const float* __restrict__ pos_f, const float4* __restrict__ grecs,
    const int* __restrict__ cntG, float4* __restrict__ meta) {
    const int bid = blockIdx.x;
    const int tid = threadIdx.x;
    if (bid < 256) {
        const int wid = tid >> 6, lane = tid & 63;
        const int bx = bid >> 2, by = bid & 3;
        const int row_base = bx * 64 + wid * 16;
        const int row_a = row_base + (lane & 15);
        const int klane = (lane >> 4) << 3;
        short8v a[4];
#pragma unroll
        for (int f = 0; f < 4; ++f)
            a[f] = *(const short8v*)(xb + (size_t)row_a * 128 + f * 32 + klane);
#pragma unroll
        for (int nt = 0; nt < 8; ++nt) {
            const int ntg = by * 8 + nt;
            f32x4 acc = {0.0f, 0.0f, 0.0f, 0.0f};
#pragma unroll
            for (int f = 0; f < 4; ++f) {
                const short8v b =
                    *(const short8v*)(WfA + (size_t)(ntg * 4 + f) * 512 + lane * 8);
                acc = __builtin_amdgcn_mfma_f32_16x16x32_bf16(a[f], b, acc, 0, 0, 0);
            }
            const int col = ntg * 16 + (lane & 15);
            const int r0 = row_base + ((lane >> 4) << 2);
#pragma unroll
            for (int r = 0; r < 4; ++r)
                RA[(size_t)(r0 + r) * 512 + col] = f2bf(acc[r]);
        }
    } else {
        const int g8 = (bid - 256) * 256 + tid;    // 131072 = 8 * NF
        const int t = g8 >> 3;
        const int sub = g8 & 7;
        const float2 p = ((const float2*)pos_f)[t];
        int cx = (int)(p.x * (float)G); cx = cx > G - 1 ? G - 1 : cx;
        int cy = (int)(p.y * (float)G); cy = cy > G - 1 ? G - 1 : cy;
        const float h = 1.0f / (float)G;

        u64 b0 = ~0ull, b1 = ~0ull, b2 = ~0ull;

        auto scan_cell = [&](int c, u64& t0, u64& t1, u64& t2) {
            const int cn = cntG[c];
            for (int i = sub; i < cn; i += 8) {
                const float4 q = grecs[(c << 5) + i];
                const float dx = p.x - q.x;
                const float dy = p.y - q.y;
                const float d = dx * dx + dy * dy;
                ins3(t0, t1, t2, ((u64)__float_as_uint(d) << 32) |
                                 (u64)__float_as_uint(q.z));
            }
        };

        {
            const int xx0 = cx - 1 < 0 ? 0 : cx - 1;
            const int xx1 = cx + 1 > G - 1 ? G - 1 : cx + 1;
            const int yy0 = cy - 1 < 0 ? 0 : cy - 1;
            const int yy1 = cy + 1 > G - 1 ? G - 1 : cy + 1;
            for (int yy = yy0; yy <= yy1; ++yy)
                for (int xx = xx0; xx <= xx1; ++xx)
                    scan_cell(yy * G + xx, b0, b1, b2);
#pragma unroll
            for (int mk = 1; mk <= 4; mk <<= 1) {
                const u64 e0 = __shfl_xor(b0, mk);
                const u64 e1 = __shfl_xor(b1, mk);
                const u64 e2 = __shfl_xor(b2, mk);
                ins3(b0, b1, b2, e0);
                ins3(b0, b1, b2, e1);
                ins3(b0, b1, b2, e2);
            }
        }

        for (int r = 2; r < G; ++r) {
            const float bd = __uint_as_float((unsigned)(b2 >> 32));
            const float lim = (float)(r - 1) * h;
            if (bd < lim * lim) break;     // NaN-safe: continues while unfilled
            u64 c0 = ~0ull, c1 = ~0ull, c2 = ~0ull;
            auto scan_full = [&](int c) {   // whole cell, this lane alone
                const int cn = cntG[c];
                for (int i = 0; i < cn; ++i) {
                    const float4 q = grecs[(c << 5) + i];
                    const float dx = p.x - q.x;
                    const float dy = p.y - q.y;
                    const float d = dx * dx + dy * dy;
                    ins3(c0, c1, c2, ((u64)__float_as_uint(d) << 32) |
                                     (u64)__float_as_uint(q.z));
                }
            };
            const int side = sub & 3, phase = sub >> 2;
            const int x0 = cx - r < 0 ? 0 : cx - r;
            const int x1 = cx + r > G - 1 ? G - 1 : cx + r;
            const int yi0 = cy - r + 1 < 0 ? 0 : cy - r + 1;
            const int yi1 = cy + r - 1 > G - 1 ? G - 1 : cy + r - 1;
            if (side == 0) {
                if (cy - r >= 0)
                    for (int xx = x0 + phase; xx <= x1; xx += 2)
                        scan_full((cy - r) * G + xx);
            } else if (side == 1) {
                if (cy + r <= G - 1)
                    for (int xx = x0 + phase; xx <= x1; xx += 2)
                        scan_full((cy + r) * G + xx);
            } else if (side == 2) {
                if (cx - r >= 0)
                    for (int yy = yi0 + phase; yy <= yi1; yy += 2)
                        scan_full(yy * G + cx - r);
            } else {
                if (cx + r <= G - 1)
                    for (int yy = yi0 + phase; yy <= yi1; yy += 2)
                        scan_full(yy * G + cx + r);
            }
#pragma unroll
            for (int mk = 1; mk <= 4; mk <<= 1) {
                const u64 e0 = __shfl_xor(c0, mk);
                const u64 e1 = __shfl_xor(c1, mk);
                const u64 e2 = __shfl_xor(c2, mk);
                ins3(c0, c1, c2, e0);
                ins3(c0, c1, c2, e1);
                ins3(c0, c1, c2, e2);
            }
            ins3(b0, b1, b2, c0);
            ins3(b0, b1, b2, c1);
            ins3(b0, b1, b2, c2);
        }

        if (sub == 0) {
            const float d0 = __uint_as_float((unsigned)(b0 >> 32));
            const float d1 = __uint_as_float((unsigned)(b1 >> 32));
            const float d2 = __uint_as_float((unsigned)(b2 >> 32));
            const float w0 = 1.0f / fmaxf(d0, 1e-16f);
            const float w1 = 1.0f / fmaxf(d1, 1e-16f);
            const float w2 = 1.0f / fmaxf(d2, 1e-16f);
            const float s = 1.0f / (w0 + w1 + w2);
            float4 mi;
            mi.x = __uint_as_float((unsigned)(b0 & 0xffffffffu));
            mi.y = __uint_as_float((unsigned)(b1 & 0xffffffffu));
            mi.z = __uint_as_float((unsigned)(b2 & 0xffffffffu));
            mi.w = 0.0f;
            float4 mw;
            mw.x = w0 * s; mw.y = w1 * s; mw.z = w2 * s; mw.w = 0.0f;
            meta[2 * t] = mi;
            meta[2 * t + 1] = mw;
        }
    }
}

// ---------------------------------------------------------------------------
// agg1: coarse aggregation (RA cols 384=P1, 448=Q1), wave-per-node, unroll 4.
// ---------------------------------------------------------------------------
__global__ __launch_bounds__(256) void agg1_kernel(
    const ushort_t* __restrict__ R, const int* __restrict__ cntC,
    const int* __restrict__ srtC, const float* __restrict__ beC,
    ushort_t* __restrict__ aggC) {
    const int n = blockIdx.x * 4 + (threadIdx.x >> 6);
    const int lane = threadIdx.x & 63;
    const int b1 = cntC[n];
    const int* bucket = srtC + n * CAPC;
    const float q = bf2f(R[(unsigned)n * 512u + 448 + lane]) + beC[lane];
    const unsigned clo = 384u + (unsigned)lane;
    float s = 0.0f;
    int e = 0;
    for (; e + 4 <= b1; e += 4) {
        const int s0 = bucket[e], s1 = bucket[e + 1];
        const int s2 = bucket[e + 2], s3 = bucket[e + 3];
        const ushort_t v0 = R[(unsigned)s0 * 512u + clo];
        const ushort_t v1 = R[(unsigned)s1 * 512u + clo];
        const ushort_t v2 = R[(unsigned)s2 * 512u + clo];
        const ushort_t v3 = R[(unsigned)s3 * 512u + clo];
        s += selu_f(bf2f(v0) + q);
        s += selu_f(bf2f(v1) + q);
        s += selu_f(bf2f(v2) + q);
        s += selu_f(bf2f(v3) + q);
    }
    for (; e < b1; ++e)
        s += selu_f(bf2f(R[(unsigned)bucket[e] * 512u + clo]) + q);
    aggC[(size_t)n * 64 + lane] = f2bf(s);
}

// ---------------------------------------------------------------------------
// nodeD: h1 = selu(concat(xb,agg1b)@Wn1 + bn1) in LDS, then RE = h1 @ WfE.
// ---------------------------------------------------------------------------
__global__ __launch_bounds__(256) void nodeD_kernel(
    const ushort_t* __restrict__ xb, const ushort_t* __restrict__ agg1b,
    const ushort_t* __restrict__ Wf1n, const float* __restrict__ bn1,
    const ushort_t* __restrict__ WfE, ushort_t* __restrict__ RE) {
    __shared__ ushort_t h1s[64][72];
    const int tid = threadIdx.x;
    const int wid = tid >> 6, lane = tid & 63;
    const int klane = (lane >> 4) << 3;
    const int row_base = blockIdx.x * 64 + wid * 16;
    const int row_a = row_base + (lane & 15);
    short8v a[6];
#pragma unroll
    for (int f = 0; f < 4; ++f)
        a[f] = *(const short8v*)(xb + (size_t)row_a * 128 + f * 32 + klane);
#pragma unroll
    for (int f = 0; f < 2; ++f)
        a[4 + f] = *(const short8v*)(agg1b + (size_t)row_a * 64 + f * 32 + klane);
#pragma unroll
    for (int nt = 0; nt < 4; ++nt) {
        f32x4 acc = {0.0f, 0.0f, 0.0f, 0.0f};
#pragma unroll
        for (int f = 0; f < 6; ++f) {
            const short8v b =
                *(const short8v*)(Wf1n + (size_t)(nt * 6 + f) * 512 + lane * 8);
            acc = __builtin_amdgcn_mfma_f32_16x16x32_bf16(a[f], b, acc, 0, 0, 0);
        }
        const int col = nt * 16 + (lane & 15);
        const int lr0 = wid * 16 + ((lane >> 4) << 2);
#pragma unroll
        for (int r = 0; r < 4; ++r)
            h1s[lr0 + r][col] = f2bf(selu_f(acc[r] + bn1[col]));
    }
    __syncthreads();
    short8v ha[2];
#pragma unroll
    for (int f = 0; f < 2; ++f)
        ha[f] = *(const short8v*)&h1s[wid * 16 + (lane & 15)][f * 32 + klane];
#pragma unroll
    for (int nt = 0; nt < 24; ++nt) {
        f32x4 acc = {0.0f, 0.0f, 0.0f, 0.0f};
#pragma unroll
        for (int f = 0; f < 2; ++f) {
            const short8v b =
                *(const short8v*)(WfE + (size_t)(nt * 2 + f) * 512 + lane * 8);
            acc = __builtin_amdgcn_mfma_f32_16x16x32_bf16(ha[f], b, acc, 0, 0, 0);
        }
        const int col = nt * 16 + (lane & 15);
        const int r0 = row_base + ((lane >> 4) << 2);
#pragma unroll
        for (int r = 0; r < 4; ++r)
            RE[(size_t)(r0 + r) * 384 + col] = f2bf(acc[r]);
    }
}

// ---------------------------------------------------------------------------
// pfBoth: per fine node, interpolate P/Q/U from RA (512) and RE (384).
// Writes interleaved PF/QF (ushort4: {S.x,S.y,2.x,2.y}) and UfS/Uf2.
// ---------------------------------------------------------------------------
__global__ __launch_bounds__(256) void pfboth_kernel(
    const ushort_t* __restrict__ RA, const ushort_t* __restrict__ RE,
    const float4* __restrict__ meta,
    const float* __restrict__ beS, const float* __restrict__ be2,
    ushort_t* __restrict__ PF, ushort_t* __restrict__ QF,
    ushort_t* __restrict__ UfS, ushort_t* __restrict__ Uf2) {
    const int gid = blockIdx.x * 256 + threadIdx.x;
    const int n = gid >> 6, lane = gid & 63;
    const float4 mi = meta[2 * n];
    const float4 mw = meta[2 * n + 1];
    const unsigned lo = (unsigned)(lane * 2);
    const unsigned i0 = __float_as_uint(mi.x);
    const unsigned i1 = __float_as_uint(mi.y);
    const unsigned i2 = __float_as_uint(mi.z);
    const unsigned a0 = i0 * 512 + lo, a1 = i1 * 512 + lo, a2 = i2 * 512 + lo;
    const unsigned e0 = i0 * 384 + lo, e1 = i1 * 384 + lo, e2 = i2 * 384 + lo;
    const ushort2 pA0 = *(const ushort2*)(RA + a0);
    const ushort2 pA1 = *(const ushort2*)(RA + a1);
    const ushort2 pA2 = *(const ushort2*)(RA + a2);
    const ushort2 qA0 = *(const ushort2*)(RA + a0 + 128);
    const ushort2 qA1 = *(const ushort2*)(RA + a1 + 128);
    const ushort2 qA2 = *(const ushort2*)(RA + a2 + 128);
    const ushort2 uA0 = *(const ushort2*)(RA + a0 + 256);
    const ushort2 uA1 = *(const ushort2*)(RA + a1 + 256);
    const ushort2 uA2 = *(const ushort2*)(RA + a2 + 256);
    const ushort2 pE0 = *(const ushort2*)(RE + e0);
    const ushort2 pE1 = *(const ushort2*)(RE + e1);
    const ushort2 pE2 = *(const ushort2*)(RE + e2);
    const ushort2 qE0 = *(const ushort2*)(RE + e0 + 128);
    const ushort2 qE1 = *(const ushort2*)(RE + e1 + 128);
    const ushort2 qE2 = *(const ushort2*)(RE + e2 + 128);
    const ushort2 uE0 = *(const ushort2*)(RE + e0 + 256);
    const ushort2 uE1 = *(const ushort2*)(RE + e1 + 256);
    const ushort2 uE2 = *(const ushort2*)(RE + e2 + 256);
    const float2 bS = *(const float2*)(beS + lane * 2);
    const float2 b2 = *(const float2*)(be2 + lane * 2);
    ushort4 pf, qf;
    pf.x = f2bf(mw.x * bf2f(pA0.x) + mw.y * bf2f(pA1.x) + mw.z * bf2f(pA2.x));
    pf.y = f2bf(mw.x * bf2f(pA0.y) + mw.y * bf2f(pA1.y) + mw.z * bf2f(pA2.y));
    pf.z = f2bf(mw.x * bf2f(pE0.x) + mw.y * bf2f(pE1.x) + mw.z * bf2f(pE2.x));
    pf.w = f2bf(mw.x * bf2f(pE0.y) + mw.y * bf2f(pE1.y) + mw.z * bf2f(pE2.y));
    *(ushort4*)(PF + (size_t)n * 256 + lane * 4) = pf;
    qf.x = f2bf(mw.x * bf2f(qA0.x) + mw.y * bf2f(qA1.x) + mw.z * bf2f(qA2.x) + bS.x);
    qf.y = f2bf(mw.x * bf2f(qA0.y) + mw.y * bf2f(qA1.y) + mw.z * bf2f(qA2.y) + bS.y);
    qf.z = f2bf(mw.x * bf2f(qE0.x) + mw.y * bf2f(qE1.x) + mw.z * bf2f(qE2.x) + b2.x);
    qf.w = f2bf(mw.x * bf2f(qE0.y) + mw.y * bf2f(qE1.y) + mw.z * bf2f(qE2.y) + b2.y);
    *(ushort4*)(QF + (size_t)n * 256 + lane * 4) = qf;
    ushort2 o;
    o.x = f2bf(mw.x * bf2f(uA0.x) + mw.y * bf2f(uA1.x) + mw.z * bf2f(uA2.x));
    o.y = f2bf(mw.x * bf2f(uA0.y) + mw.y * bf2f(uA1.y) + mw.z * bf2f(uA2.y));
    *(ushort2*)(UfS + (size_t)n * 128 + lo) = o;
    o.x = f2bf(mw.x * bf2f(uE0.x) + mw.y * bf2f(uE1.x) + mw.z * bf2f(uE2.x));
    o.y = f2bf(mw.x * bf2f(uE0.y) + mw.y * bf2f(uE1.y) + mw.z * bf2f(uE2.y));
    *(ushort2*)(Uf2 + (size_t)n * 128 + lo) = o;
}

// ---------------------------------------------------------------------------
// aggBoth: one edge traversal, both aggregations, ONE 8B gather per edge.
// ---------------------------------------------------------------------------
__global__ __launch_bounds__(256) void aggboth_kernel(
    const ushort_t* __restrict__ PF, const ushort_t* __restrict__ QF,
    const int* __restrict__ cntF, const int* __restrict__ srtF,
    ushort_t* __restrict__ aggS, ushort_t* __restrict__ agg2) {
    const int n = blockIdx.x * 4 + (threadIdx.x >> 6);
    const int lane = threadIdx.x & 63;
    const unsigned lo4 = (unsigned)(lane * 4);
    const ushort4 qv = *(const ushort4*)(QF + (size_t)n * 256 + lo4);
    const float qSx = bf2f(qv.x), qSy = bf2f(qv.y);
    const float q2x = bf2f(qv.z), q2y = bf2f(qv.w);
    const int b1 = cntF[n];
    const int* bucket = srtF + n * CAPF;
    float aSx = 0.0f, aSy = 0.0f, a2x = 0.0f, a2y = 0.0f;
    int e = 0;
    for (; e + 8 <= b1; e += 8) {
        int s[8];
#pragma unroll
        for (int j = 0; j < 8; ++j) s[j] = bucket[e + j];
        ushort4 g[8];
#pragma unroll
        for (int j = 0; j < 8; ++j)
            g[j] = *(const ushort4*)(PF + (unsigned)s[j] * 256u + lo4);
#pragma unroll
        for (int j = 0; j < 8; ++j) {
            aSx += selu_f(bf2f(g[j].x) + qSx);
            aSy += selu_f(bf2f(g[j].y) + qSy);
            a2x += selu_f(bf2f(g[j].z) + q2x);
            a2y += selu_f(bf2f(g[j].w) + q2y);
        }
    }
    if (e < b1) {
        int s[8];
        ushort4 g[8];
        const int m = b1 - e;
#pragma unroll
        for (int j = 0; j < 8; ++j)
            s[j] = (j < m) ? bucket[e + j] : s[0];
#pragma unroll
        for (int j = 0; j < 8; ++j)
            g[j] = *(const ushort4*)(PF + (unsigned)s[j] * 256u + lo4);
#pragma unroll
        for (int j = 0; j < 8; ++j) {
            if (j < m) {
                aSx += selu_f(bf2f(g[j].x) + qSx);
                aSy += selu_f(bf2f(g[j].y) + qSy);
                a2x += selu_f(bf2f(g[j].z) + q2x);
                a2y += selu_f(bf2f(g[j].w) + q2y);
            }
        }
    }
    const unsigned lo = (unsigned)(lane * 2);
    ushort2 r;
    r.x = f2bf(aSx); r.y = f2bf(aSy);
    *(ushort2*)(aggS + (size_t)n * 128 + lo) = r;
    r.x = f2bf(a2x); r.y = f2bf(a2y);
    *(ushort2*)(agg2 + (size_t)n * 128 + lo) = r;
}

// ---------------------------------------------------------------------------
// nodeFinal: x_skip = selu(aggS@WfSn + UfS + bnS) (registers)
//            h      = selu(agg2@Wf2n + Uf2 + bn2)
//            v = h + x_skip -> outp; BN stats accumulated.
// ---------------------------------------------------------------------------
__global__ __launch_bounds__(256) void nodeF_kernel(
    const ushort_t* __restrict__ aggS, const ushort_t* __restrict__ WfSn,
    const float* __restrict__ bnS, const ushort_t* __restrict__ UfS,
    const ushort_t* __restrict__ agg2, const ushort_t* __restrict__ Wf2n,
    const float* __restrict__ bn2, const ushort_t* __restrict__ Uf2,
    float* __restrict__ outp, float* __restrict__ stats) {
    __shared__ float s_sum[128], s_sq[128];
    const int tid = threadIdx.x;
    const int wid = tid >> 6, lane = tid & 63;
    const int klane = (lane >> 4) << 3;
    if (tid < 128) { s_sum[tid] = 0.0f; s_sq[tid] = 0.0f; }
    __syncthreads();
    const int row_base = blockIdx.x * 64 + wid * 16;
    const int row_a = row_base + (lane & 15);
    short8v aS[4], a2[4];
#pragma unroll
    for (int f = 0; f < 4; ++f) {
        aS[f] = *(const short8v*)(aggS + (size_t)row_a * 128 + f * 32 + klane);
        a2[f] = *(const short8v*)(agg2 + (size_t)row_a * 128 + f * 32 + klane);
    }
#pragma unroll
    for (int nt = 0; nt < 8; ++nt) {
        f32x4 accS = {0.0f, 0.0f, 0.0f, 0.0f};
        f32x4 acc2 = {0.0f, 0.0f, 0.0f, 0.0f};
#pragma unroll
        for (int f = 0; f < 4; ++f) {
            const short8v bS =
                *(const short8v*)(WfSn + (size_t)(nt * 4 + f) * 512 + lane * 8);
            const short8v b2 =
                *(const short8v*)(Wf2n + (size_t)(nt * 4 + f) * 512 + lane * 8);
            accS = __builtin_amdgcn_mfma_f32_16x16x32_bf16(aS[f], bS, accS, 0, 0, 0);
            acc2 = __builtin_amdgcn_mfma_f32_16x16x32_bf16(a2[f], b2, acc2, 0, 0, 0);
        }
        const int col = nt * 16 + (lane & 15);
        const int r0 = row_base + ((lane >> 4) << 2);
        float lsum = 0.0f, lsq = 0.0f;
#pragma unroll
        for (int r = 0; r < 4; ++r) {
            const size_t o = (size_t)(r0 + r) * 128 + col;
            const float xs = selu_f(accS[r] + bnS[col] + bf2f(UfS[o]));
            const float hh = selu_f(acc2[r] + bn2[col] + bf2f(Uf2[o]));
            const float v = hh + xs;
            outp[o] = v;
            lsum += v; lsq += v * v;
        }
        atomicAdd(&s_sum[nt * 16 + (lane & 15)], lsum);
        atomicAdd(&s_sq[nt * 16 + (lane & 15)], lsq);
    }
    __syncthreads();
    if (tid < 128) {
        atomicAdd(&stats[tid], s_sum[tid]);
        atomicAdd(&stats[128 + tid], s_sq[tid]);
    }
}

// ---------------------------------------------------------------------------
// BN normalize + SELU, in place on d_out.
// ---------------------------------------------------------------------------
__global__ __launch_bounds__(256) void bn_kernel(
    float* __restrict__ out, const float* __restrict__ stats,
    const float* __restrict__ gamma, const float* __restrict__ beta, int Nn) {
    const int i = blockIdx.x * blockDim.x + threadIdx.x;
    const int c = i & 127;
    const float invn = 1.0f / (float)Nn;
    float mu = stats[c] * invn;
    float var = stats[128 + c] * invn - mu * mu;
    float r = rsqrtf(var + 1e-5f);
    float v = (out[i] - mu) * r * gamma[c] + beta[c];
    out[i] = selu_f(v);
}

// ---------------------------------------------------------------------------
extern "C" void kernel_launch(void* const* d_in, const int* in_sizes, int n_in,
                              void* d_out, int out_size, void* d_ws, size_t ws_size,
                              hipStream_t stream) {
    const float* x     = (const float*)d_in[0];
    const float* pos_c = (const float*)d_in[1];
    const float* pos_f = (const float*)d_in[2];
    const int*   ei_c  = (const int*)d_in[3];
    const int*   ei_f  = (const int*)d_in[4];
    const float* We1 = (const float*)d_in[5];
    const float* be1 = (const float*)d_in[6];
    const float* Wn1 = (const float*)d_in[7];
    const float* bn1 = (const float*)d_in[8];
    const float* We2 = (const float*)d_in[9];
    const float* be2 = (const float*)d_in[10];
    const float* Wn2 = (const float*)d_in[11];
    const float* bn2 = (const float*)d_in[12];
    const float* WeS = (const float*)d_in[13];
    const float* beS = (const float*)d_in[14];
    const float* WnS = (const float*)d_in[15];
    const float* bnS = (const float*)d_in[16];
    const float* gamma = (const float*)d_in[17];
    const float* beta  = (const float*)d_in[18];

    char* w = (char*)d_ws;
    size_t o = 0;
    auto alloc = [&](size_t bytes) { void* p = w + o; o += (bytes + 255) & ~(size_t)255; return p; };
    float4*   meta    = (float4*)alloc((size_t)NF * 2 * sizeof(float4));
    ushort_t* RA      = (ushort_t*)alloc((size_t)NC * 512 * 2);
    ushort_t* RE      = (ushort_t*)alloc((size_t)NC * 384 * 2);
    ushort_t* PF      = (ushort_t*)alloc((size_t)NF * 256 * 2);
    ushort_t* QF      = (ushort_t*)alloc((size_t)NF * 256 * 2);
    ushort_t* UfS     = (ushort_t*)alloc((size_t)NF * 128 * 2);
    ushort_t* Uf2     = (ushort_t*)alloc((size_t)NF * 128 * 2);
    ushort_t* aggS    = (ushort_t*)alloc((size_t)NF * 128 * 2);
    ushort_t* agg2    = (ushort_t*)alloc((size_t)NF * 128 * 2);
    ushort_t* agg1b   = (ushort_t*)alloc((size_t)NC * 64 * 2);
    ushort_t* xb      = (ushort_t*)alloc((size_t)NC * 128 * 2);
    ushort_t* WfA     = (ushort_t*)alloc(65536 * 2);
    ushort_t* WfE     = (ushort_t*)alloc(24576 * 2);
    ushort_t* WfSn    = (ushort_t*)alloc(16384 * 2);
    ushort_t* Wf1n    = (ushort_t*)alloc(12288 * 2);
    ushort_t* Wf2n    = (ushort_t*)alloc(16384 * 2);
    int*   cntF  = (int*)alloc((size_t)NF * sizeof(int));
    int*   srtF  = (int*)alloc((size_t)NF * CAPF * sizeof(int));
    int*   cntC  = (int*)alloc((size_t)NC * sizeof(int));
    int*   srtC  = (int*)alloc((size_t)NC * CAPC * sizeof(int));
    int*   cntG  = (int*)alloc((size_t)NCELL * sizeof(int));
    float4* grecs = (float4*)alloc((size_t)NCELL * CAPG * sizeof(float4));
    float* stats = (float*)alloc(256 * sizeof(float));
    float* outp = (float*)d_out;

    // 1. prep (converts + weight frags + zero counters/stats)
    constexpr int PREP_TOTAL = NC * 128 + 65536 + 24576 + 16384 + 12288 + 16384
                             + NF + NC + NCELL + 256;
    prep_kernel<<<(PREP_TOTAL + 255) / 256, 256, 0, stream>>>(
        x, xb, WeS, WnS, We1, We2, Wn2, Wn1,
        WfA, WfE, WfSn, Wf1n, Wf2n, cntF, cntC, cntG, stats);

    // 2. direct scatter into fixed-stride buckets
    constexpr int SORT_ITEMS = EF + EC + NC;
    scatter_kernel<<<(SORT_ITEMS + 255) / 256, 256, 0, stream>>>(
        ei_f, ei_c, pos_c, cntF, srtF, cntC, srtC, cntG, grecs);

    // 3. RA GEMM (bf16 out) + kNN
    gemmA_knn_kernel<<<768, 256, 0, stream>>>(
        xb, WfA, RA, pos_f, grecs, cntG, meta);

    // 4. coarse aggregation (mpl1)
    agg1_kernel<<<NC / 4, 256, 0, stream>>>(RA, cntC, srtC, be1, agg1b);

    // 5. node1 + gemmE -> RE
    nodeD_kernel<<<NC / 64, 256, 0, stream>>>(xb, agg1b, Wf1n, bn1, WfE, RE);

    // 6. pfBoth: interpolate P/Q/U from RA and RE (interleaved PF/QF)
    pfboth_kernel<<<NF / 4, 256, 0, stream>>>(
        RA, RE, meta, beS, be2, PF, QF, UfS, Uf2);

    // 7. aggBoth: single edge traversal, one gather per edge
    aggboth_kernel<<<NF / 4, 256, 0, stream>>>(
        PF, QF, cntF, srtF, aggS, agg2);

    // 8. nodeFinal: both node GEMMs + residual + BN stats
    nodeF_kernel<<<NF / 64, 256, 0, stream>>>(
        aggS, WfSn, bnS, UfS, agg2, Wf2n, bn2, Uf2, outp, stats);

    // 9. BN + SELU
    bn_kernel<<<NF * 128 / 256, 256, 0, stream>>>(outp, stats, gamma, beta, NF);
}